// Round 4
// baseline (510.289 us; speedup 1.0000x reference)
//
#include <hip/hip_runtime.h>
#include <hip/hip_bf16.h>
#include <math.h>

typedef __bf16 bf16x8 __attribute__((ext_vector_type(8)));
typedef float  f32x4  __attribute__((ext_vector_type(4)));

#define GLD16(g, l) __builtin_amdgcn_global_load_lds(                      \
    (const __attribute__((address_space(1))) void*)(g),                    \
    (__attribute__((address_space(3))) void*)(l), 16, 0, 0)

// ---------------- transpose + f32 -> bf16 convert (out[c][r] = in[r][c]) ----
__global__ __launch_bounds__(256) void tconv_k(const float* __restrict__ in,
                                               __bf16* __restrict__ out,
                                               int ldin, int ldout) {
  __shared__ float t[32][33];
  int c0 = blockIdx.x * 32, r0 = blockIdx.y * 32;
  int tx = threadIdx.x & 31, ty = threadIdx.x >> 5;
  #pragma unroll
  for (int i = ty; i < 32; i += 8)
    t[i][tx] = in[(size_t)(r0 + i) * ldin + c0 + tx];
  __syncthreads();
  #pragma unroll
  for (int i = ty; i < 32; i += 8)
    out[(size_t)(c0 + i) * ldout + r0 + tx] = (__bf16)t[tx][i];
}

// ---------------- RMSNorm: x = h * rsqrt(mean(h^2) + eps), bf16 out --------
__global__ __launch_bounds__(256) void rmsnorm_k(const float* __restrict__ hs,
                                                 __bf16* __restrict__ x) {
  int row = blockIdx.x, tid = threadIdx.x;
  const float4 v = ((const float4*)(hs + (size_t)row * 1024))[tid];
  float ss = v.x * v.x + v.y * v.y + v.z * v.z + v.w * v.w;
  #pragma unroll
  for (int o = 32; o > 0; o >>= 1) ss += __shfl_xor(ss, o);
  __shared__ float ps[4];
  if ((tid & 63) == 0) ps[tid >> 6] = ss;
  __syncthreads();
  float tot = ps[0] + ps[1] + ps[2] + ps[3];
  float r = rsqrtf(tot * (1.0f / 1024.0f) + 1.1920929e-7f);
  __bf16* xr = x + (size_t)row * 1024 + tid * 4;
  xr[0] = (__bf16)(v.x * r); xr[1] = (__bf16)(v.y * r);
  xr[2] = (__bf16)(v.z * r); xr[3] = (__bf16)(v.w * r);
}

// ---------------- GEMM 128x128, double-buffered LDS, optional split-K ------
// C(MxN,f32) = A(MxK,bf16) * Bt(NxK,bf16)^T.  grid.z>1: K split, partials
// atomicAdd'ed into zero-initialized C; kz==0 carries bias/add1/lam*addh.
// One barrier per K-iter: prefetch tile i+1 into buf[(i+1)&1] right after
// the barrier, compute tile i — the vmcnt(0) drain at the next barrier then
// happens after a full compute phase has covered most of the load latency.
__global__ __launch_bounds__(256) void gemm_bt_k(
    const __bf16* __restrict__ A, const __bf16* __restrict__ Bt,
    float* __restrict__ C, int N, int K,
    const float* __restrict__ bias, const float* __restrict__ add1,
    const float* __restrict__ addh, const float* __restrict__ plam) {
  __shared__ __bf16 sA[2][128 * 32];
  __shared__ __bf16 sB[2][128 * 32];
  const int tid = threadIdx.x;
  const int lane = tid & 63;
  const int quad = lane >> 4, l16 = lane & 15;
  const int wave = tid >> 6;
  const int waveM = wave >> 1, waveN = wave & 1;
  const int m0 = blockIdx.y * 128, n0 = blockIdx.x * 128;
  const int kz = blockIdx.z, nz = gridDim.z;
  const int kper = K / nz, kbeg = kz * kper;
  const int nk = kper >> 5;
  const int rowS = tid >> 2;
  const int kgS = (tid & 3) * 8;
  const __bf16* gA0 = A + (size_t)(m0 + rowS) * K + kbeg + kgS;
  const __bf16* gA1 = gA0 + (size_t)64 * K;
  const __bf16* gB0 = Bt + (size_t)(n0 + rowS) * K + kbeg + kgS;
  const __bf16* gB1 = gB0 + (size_t)64 * K;
  const int lo0 = tid * 8, lo1 = 2048 + tid * 8;

  // prologue: stage tile 0 into buf 0
  GLD16(gA0, sA[0] + lo0);
  GLD16(gA1, sA[0] + lo1);
  GLD16(gB0, sB[0] + lo0);
  GLD16(gB1, sB[0] + lo1);

  f32x4 acc[4][4] = {};
  for (int i = 0; i < nk; ++i) {
    __syncthreads();   // drains prefetch of buf[i&1]; syncs readers of buf[(i+1)&1]
    if (i + 1 < nk) {
      const int k = (i + 1) * 32;
      __bf16* dA = sA[(i + 1) & 1];
      __bf16* dB = sB[(i + 1) & 1];
      GLD16(gA0 + k, dA + lo0);
      GLD16(gA1 + k, dA + lo1);
      GLD16(gB0 + k, dB + lo0);
      GLD16(gB1 + k, dB + lo1);
    }
    const __bf16* cA = sA[i & 1];
    const __bf16* cB = sB[i & 1];
    bf16x8 af[4], bfv[4];
    #pragma unroll
    for (int mt = 0; mt < 4; ++mt)
      af[mt] = *(const bf16x8*)(cA + (waveM * 64 + mt * 16 + l16) * 32 + quad * 8);
    #pragma unroll
    for (int nt = 0; nt < 4; ++nt)
      bfv[nt] = *(const bf16x8*)(cB + (waveN * 64 + nt * 16 + l16) * 32 + quad * 8);
    #pragma unroll
    for (int mt = 0; mt < 4; ++mt)
      #pragma unroll
      for (int nt = 0; nt < 4; ++nt)
        acc[mt][nt] = __builtin_amdgcn_mfma_f32_16x16x32_bf16(af[mt], bfv[nt], acc[mt][nt], 0, 0, 0);
  }

  const bool primary = (kz == 0);
  float lam = (addh && primary) ? plam[0] : 0.f;
  #pragma unroll
  for (int mt = 0; mt < 4; ++mt) {
    int row = m0 + waveM * 64 + mt * 16 + quad * 4;
    #pragma unroll
    for (int nt = 0; nt < 4; ++nt) {
      int col = n0 + waveN * 64 + nt * 16 + l16;
      float b = (bias && primary) ? bias[col] : 0.f;
      #pragma unroll
      for (int r = 0; r < 4; ++r) {
        size_t idx = (size_t)(row + r) * N + col;
        float v = acc[mt][nt][r] + b;
        if (primary) {
          if (add1) v += add1[idx];
          if (addh) v += lam * addh[idx];
        }
        if (nz == 1) C[idx] = v;
        else atomicAdd(&C[idx], v);
      }
    }
  }
}

// ---------------- l2norm + RoPE for q,k,qb,kb --------------------------------
__global__ __launch_bounds__(256) void qkprep_k(const float* __restrict__ proj,
    __bf16* __restrict__ qo, __bf16* __restrict__ ko,
    float* __restrict__ qbo, float* __restrict__ kbo) {
  int gw = blockIdx.x * 4 + (threadIdx.x >> 6);
  int lane = threadIdx.x & 63;
  int s = gw >> 4, h = gw & 15;
  int j = lane & 31;
  float inv = powf(1000.0f, -(float)j * (1.0f / 32.0f));
  float ang = (float)s * inv;
  float cb = (float)(__bf16)cosf(ang);
  float sb = (float)(__bf16)sinf(ang);
  size_t ibase = (size_t)s * 5120 + h * 64 + lane;
  size_t obase = (size_t)s * 1024 + h * 64 + lane;
  bool lo = lane < 32;

  auto proc = [&](const float* src) -> float {
    float xv = src[ibase];
    float ss = xv * xv;
    #pragma unroll
    for (int o = 32; o > 0; o >>= 1) ss += __shfl_xor(ss, o);
    float y = xv / fmaxf(sqrtf(ss), 1e-12f);
    float yp = __shfl_xor(y, 32);
    return lo ? (y * cb + yp * sb) : (y * cb - yp * sb);
  };
  qo[obase]  = (__bf16)proc(proj + 0);
  ko[obase]  = (__bf16)proc(proj + 1024);
  qbo[obase] = proc(proj + 3072);
  kbo[obase] = proc(proj + 4096);
}

// ---------------- sb row-sum via two-level cumsum ---------------------------
__global__ __launch_bounds__(64) void kbsum_k(const float* __restrict__ kb,
                                              float* __restrict__ tsum) {
  int t = blockIdx.x, h = blockIdx.y, d = threadIdx.x;
  size_t base = (size_t)h * 64 + d;
  float s = 0.f;
  #pragma unroll 4
  for (int r = 0; r < 32; ++r)
    s += kb[(size_t)(t * 32 + r) * 1024 + base];
  tsum[(t * 16 + h) * 64 + d] = s;
}

__global__ __launch_bounds__(64) void sbrow2_k(const float* __restrict__ qb,
                                               const float* __restrict__ kb,
                                               const float* __restrict__ tsum,
                                               float* __restrict__ sb) {
  int t = blockIdx.x, h = blockIdx.y, d = threadIdx.x;
  size_t base = (size_t)h * 64 + d;
  float run = 0.f;
  for (int tp = 0; tp < t; ++tp) run += tsum[(tp * 16 + h) * 64 + d];
  for (int s0 = 0; s0 < 32; s0 += 4) {
    float p[4];
    #pragma unroll
    for (int u = 0; u < 4; ++u) {
      size_t off = (size_t)(t * 32 + s0 + u) * 1024 + base;
      run += kb[off];
      p[u] = qb[off] * run;
    }
    #pragma unroll
    for (int o = 32; o > 0; o >>= 1) {
      #pragma unroll
      for (int u = 0; u < 4; ++u) p[u] += __shfl_xor(p[u], o);
    }
    if (d == 0) {
      #pragma unroll
      for (int u = 0; u < 4; ++u) sb[(t * 32 + s0 + u) * 16 + h] = 0.125f * p[u];
    }
  }
}

// ---------------- flash attention v2: register softmax, balanced pairing ----
__global__ __launch_bounds__(256) void attn_k(const __bf16* __restrict__ qg,
    const __bf16* __restrict__ kg, const __bf16* __restrict__ vtg,
    const float* __restrict__ sbr, const float* __restrict__ pl2s,
    __bf16* __restrict__ yo) {
  __shared__ __bf16 sK[64 * 64];
  __shared__ __bf16 sVt[64 * 64];
  __shared__ __bf16 sP[64 * 72];
  const int pair = blockIdx.x, hh = blockIdx.y;
  const int tid = threadIdx.x, lane = tid & 63, w = tid >> 6;
  const int quad = lane >> 4, l16 = lane & 15;
  const float l2s = pl2s[0];
  const int rS = tid >> 3, cS = (tid & 7) * 8;
  __bf16* ldsK = sK + tid * 8;
  __bf16* ldsV = sVt + tid * 8;

  for (int phase = 0; phase < 2; ++phase) {
    const int qt = (phase == 0) ? pair : 31 - pair;
    const int q0 = qt * 64;
    bf16x8 qf[2];
    #pragma unroll
    for (int kk = 0; kk < 2; ++kk)
      qf[kk] = *(const bf16x8*)(qg + (size_t)(q0 + w * 16 + l16) * 1024 + hh * 64 + kk * 32 + quad * 8);
    f32x4 accO[4] = {};
    float m_[4], l_[4];
    #pragma unroll
    for (int r = 0; r < 4; ++r) { m_[r] = -INFINITY; l_[r] = 0.f; }

    for (int kt = 0; kt <= qt; ++kt) {
      const __bf16* gK = kg + (size_t)(kt * 64 + rS) * 1024 + hh * 64 + cS;
      const __bf16* gV = vtg + (size_t)(hh * 64 + rS) * 2048 + kt * 64 + cS;
      GLD16(gK, ldsK);
      GLD16(gK + (size_t)32 * 1024, ldsK + 2048);
      GLD16(gV, ldsV);
      GLD16(gV + (size_t)32 * 2048, ldsV + 2048);
      __syncthreads();

      f32x4 s4[4];
      #pragma unroll
      for (int nt = 0; nt < 4; ++nt) {
        bf16x8 b0 = *(const bf16x8*)(sK + (nt * 16 + l16) * 64 + quad * 8);
        bf16x8 b1 = *(const bf16x8*)(sK + (nt * 16 + l16) * 64 + 32 + quad * 8);
        f32x4 sa = {0.f, 0.f, 0.f, 0.f};
        sa = __builtin_amdgcn_mfma_f32_16x16x32_bf16(qf[0], b0, sa, 0, 0, 0);
        sa = __builtin_amdgcn_mfma_f32_16x16x32_bf16(qf[1], b1, sa, 0, 0, 0);
        s4[nt] = sa;
      }
      if (kt == qt) {
        #pragma unroll
        for (int nt = 0; nt < 4; ++nt)
          #pragma unroll
          for (int r = 0; r < 4; ++r)
            if (nt * 16 + l16 > w * 16 + quad * 4 + r) s4[nt][r] = -INFINITY;
      }
      float mx[4], al[4], rs[4];
      #pragma unroll
      for (int r = 0; r < 4; ++r)
        mx[r] = fmaxf(fmaxf(s4[0][r], s4[1][r]), fmaxf(s4[2][r], s4[3][r]));
      #pragma unroll
      for (int o = 1; o < 16; o <<= 1)
        #pragma unroll
        for (int r = 0; r < 4; ++r) mx[r] = fmaxf(mx[r], __shfl_xor(mx[r], o));
      #pragma unroll
      for (int r = 0; r < 4; ++r) {
        float mn = fmaxf(m_[r], mx[r]);
        al[r] = __expf(m_[r] - mn);
        m_[r] = mn;
      }
      float p[4][4];
      #pragma unroll
      for (int nt = 0; nt < 4; ++nt)
        #pragma unroll
        for (int r = 0; r < 4; ++r)
          p[nt][r] = __expf(s4[nt][r] - m_[r]);
      #pragma unroll
      for (int r = 0; r < 4; ++r)
        rs[r] = (p[0][r] + p[1][r]) + (p[2][r] + p[3][r]);
      #pragma unroll
      for (int o = 1; o < 16; o <<= 1)
        #pragma unroll
        for (int r = 0; r < 4; ++r) rs[r] += __shfl_xor(rs[r], o);
      #pragma unroll
      for (int r = 0; r < 4; ++r) l_[r] = l_[r] * al[r] + rs[r];
      #pragma unroll
      for (int nt = 0; nt < 4; ++nt)
        #pragma unroll
        for (int r = 0; r < 4; ++r) accO[nt][r] *= al[r];
      #pragma unroll
      for (int nt = 0; nt < 4; ++nt)
        #pragma unroll
        for (int r = 0; r < 4; ++r)
          sP[(w * 16 + quad * 4 + r) * 72 + nt * 16 + l16] = (__bf16)p[nt][r];
      #pragma unroll
      for (int kk = 0; kk < 2; ++kk) {
        bf16x8 a = *(const bf16x8*)(sP + (w * 16 + l16) * 72 + kk * 32 + quad * 8);
        #pragma unroll
        for (int nt = 0; nt < 4; ++nt) {
          bf16x8 bv = *(const bf16x8*)(sVt + (nt * 16 + l16) * 64 + kk * 32 + quad * 8);
          accO[nt] = __builtin_amdgcn_mfma_f32_16x16x32_bf16(a, bv, accO[nt], 0, 0, 0);
        }
      }
      __syncthreads();
    }
    #pragma unroll
    for (int nt = 0; nt < 4; ++nt) {
      int dcol = nt * 16 + l16;
      #pragma unroll
      for (int r = 0; r < 4; ++r) {
        int grow = q0 + w * 16 + quad * 4 + r;
        float val = l2s * accO[nt][r] / l_[r] + sbr[grow * 16 + hh];
        yo[(size_t)grow * 1024 + hh * 64 + dcol] = (__bf16)val;
      }
    }
  }
}

// ---------------- SwiGLU: ffin = silu(u[:,4096+i]) * u[:,i], bf16 ----------
__global__ __launch_bounds__(256) void silu_k(const float* __restrict__ u,
                                              __bf16* __restrict__ ffin) {
  int i = blockIdx.x * 256 + threadIdx.x;
  int s = i >> 10, c = (i & 1023) * 4;
  const float4 xp = *(const float4*)(u + (size_t)s * 8192 + c);
  const float4 g  = *(const float4*)(u + (size_t)s * 8192 + 4096 + c);
  __bf16* o = ffin + (size_t)s * 4096 + c;
  o[0] = (__bf16)(xp.x * g.x / (1.f + expf(-g.x)));
  o[1] = (__bf16)(xp.y * g.y / (1.f + expf(-g.y)));
  o[2] = (__bf16)(xp.z * g.z / (1.f + expf(-g.z)));
  o[3] = (__bf16)(xp.w * g.w / (1.f + expf(-g.w)));
}

extern "C" void kernel_launch(void* const* d_in, const int* in_sizes, int n_in,
                              void* d_out, int out_size, void* d_ws, size_t ws_size,
                              hipStream_t stream) {
  (void)in_sizes; (void)n_in; (void)ws_size;
  const float* hs   = (const float*)d_in[0];
  const float* Wq   = (const float*)d_in[1];
  const float* Wk   = (const float*)d_in[2];
  const float* Wv   = (const float*)d_in[3];
  const float* Wqb  = (const float*)d_in[4];
  const float* Wkb  = (const float*)d_in[5];
  const float* Wo   = (const float*)d_in[6];
  const float* bo   = (const float*)d_in[7];
  const float* W1   = (const float*)d_in[8];
  const float* b1   = (const float*)d_in[9];
  const float* W2   = (const float*)d_in[10];
  const float* b2   = (const float*)d_in[11];
  const float* plam = (const float*)d_in[12];
  const float* pl2s = (const float*)d_in[13];
  float* out = (float*)d_out;
  char* ws = (char*)d_ws;

  size_t off = 0;
  auto alloc = [&](size_t bytes) { char* p = ws + off; off += (bytes + 255) & ~(size_t)255; return p; };
  __bf16* Wt5  = (__bf16*)alloc((size_t)5 * 1024 * 1024 * 2);
  __bf16* Wot  = (__bf16*)alloc((size_t)1024 * 1024 * 2);
  __bf16* W1t  = (__bf16*)alloc((size_t)8192 * 1024 * 2);
  __bf16* W2t  = (__bf16*)alloc((size_t)1024 * 4096 * 2);
  __bf16* xbf  = (__bf16*)alloc((size_t)2048 * 1024 * 2);
  char* ureg = ws + off;  // u (64 MB) aliases [proj,qbf32,kbf32,qbf,kbf]
  float*  proj  = (float*)alloc((size_t)2048 * 5120 * 4);
  float*  qbf32 = (float*)alloc((size_t)2048 * 1024 * 4);
  float*  kbf32 = (float*)alloc((size_t)2048 * 1024 * 4);
  __bf16* qbf   = (__bf16*)alloc((size_t)2048 * 1024 * 2);
  __bf16* kbf   = (__bf16*)alloc((size_t)2048 * 1024 * 2);
  float*  u     = (float*)ureg;
  __bf16* vtbf  = (__bf16*)alloc((size_t)1024 * 2048 * 2);
  __bf16* ybf   = (__bf16*)alloc((size_t)2048 * 1024 * 2);
  float*  sbrow = (float*)alloc((size_t)2048 * 16 * 4);
  float*  tsum  = (float*)alloc((size_t)64 * 16 * 64 * 4);
  float*  attn  = (float*)alloc((size_t)2048 * 1024 * 4);
  __bf16* ffin  = (__bf16*)alloc((size_t)2048 * 4096 * 2);

  // zero split-K accumulation targets (atomicAdd destinations)
  hipMemsetAsync(attn, 0, (size_t)2048 * 1024 * 4, stream);
  hipMemsetAsync(out, 0, (size_t)out_size * 4, stream);

  tconv_k<<<dim3(32, 32), 256, 0, stream>>>(Wq,  Wt5,               1024, 1024);
  tconv_k<<<dim3(32, 32), 256, 0, stream>>>(Wk,  Wt5 + 1048576,     1024, 1024);
  tconv_k<<<dim3(32, 32), 256, 0, stream>>>(Wv,  Wt5 + 2 * 1048576, 1024, 1024);
  tconv_k<<<dim3(32, 32), 256, 0, stream>>>(Wqb, Wt5 + 3 * 1048576, 1024, 1024);
  tconv_k<<<dim3(32, 32), 256, 0, stream>>>(Wkb, Wt5 + 4 * 1048576, 1024, 1024);
  tconv_k<<<dim3(32, 32), 256, 0, stream>>>(Wo,  Wot,               1024, 1024);
  tconv_k<<<dim3(256, 32), 256, 0, stream>>>(W1, W1t,               8192, 1024);
  tconv_k<<<dim3(32, 128), 256, 0, stream>>>(W2, W2t,               1024, 4096);

  rmsnorm_k<<<2048, 256, 0, stream>>>(hs, xbf);
  gemm_bt_k<<<dim3(40, 16, 1), 256, 0, stream>>>(xbf, Wt5, proj, 5120, 1024,
                                                 nullptr, nullptr, nullptr, nullptr);
  qkprep_k<<<8192, 256, 0, stream>>>(proj, qbf, kbf, qbf32, kbf32);
  tconv_k<<<dim3(32, 64), 256, 0, stream>>>(proj + 2048, vtbf, 5120, 2048);
  kbsum_k<<<dim3(64, 16), 64, 0, stream>>>(kbf32, tsum);
  sbrow2_k<<<dim3(64, 16), 64, 0, stream>>>(qbf32, kbf32, tsum, sbrow);
  attn_k<<<dim3(16, 16), 256, 0, stream>>>(qbf, kbf, vtbf, sbrow, pl2s, ybf);
  // attn_out = y @ Wo + bo   (split-K x4 -> 512 blocks)
  gemm_bt_k<<<dim3(8, 16, 4), 256, 0, stream>>>(ybf, Wot, attn, 1024, 1024,
                                                bo, nullptr, nullptr, nullptr);
  gemm_bt_k<<<dim3(64, 16, 1), 256, 0, stream>>>(xbf, W1t, u, 8192, 1024,
                                                 b1, nullptr, nullptr, nullptr);
  silu_k<<<8192, 256, 0, stream>>>(u, ffin);
  // out = ffin @ W2 + b2 + attn + lam*h   (split-K x4 -> 512 blocks)
  gemm_bt_k<<<dim3(8, 16, 4), 256, 0, stream>>>(ffin, W2t, out, 1024, 4096,
                                                b2, attn, hs, plam);
}

// Round 5
// 426.023 us; speedup vs baseline: 1.1978x; 1.1978x over previous
//
#include <hip/hip_runtime.h>
#include <hip/hip_bf16.h>
#include <math.h>

typedef __bf16 bf16x8 __attribute__((ext_vector_type(8)));
typedef float  f32x4  __attribute__((ext_vector_type(4)));

#define GLD16(g, l) __builtin_amdgcn_global_load_lds(                      \
    (const __attribute__((address_space(1))) void*)(g),                    \
    (__attribute__((address_space(3))) void*)(l), 16, 0, 0)

// ---------------- transpose + f32 -> bf16 convert (out[c][r] = in[r][c]) ----
__global__ __launch_bounds__(256) void tconv_k(const float* __restrict__ in,
                                               __bf16* __restrict__ out,
                                               int ldin, int ldout) {
  __shared__ float t[32][33];
  int c0 = blockIdx.x * 32, r0 = blockIdx.y * 32;
  int tx = threadIdx.x & 31, ty = threadIdx.x >> 5;
  #pragma unroll
  for (int i = ty; i < 32; i += 8)
    t[i][tx] = in[(size_t)(r0 + i) * ldin + c0 + tx];
  __syncthreads();
  #pragma unroll
  for (int i = ty; i < 32; i += 8)
    out[(size_t)(c0 + i) * ldout + r0 + tx] = (__bf16)t[tx][i];
}

// ---------------- RMSNorm ---------------------------------------------------
__global__ __launch_bounds__(256) void rmsnorm_k(const float* __restrict__ hs,
                                                 __bf16* __restrict__ x) {
  int row = blockIdx.x, tid = threadIdx.x;
  const float4 v = ((const float4*)(hs + (size_t)row * 1024))[tid];
  float ss = v.x * v.x + v.y * v.y + v.z * v.z + v.w * v.w;
  #pragma unroll
  for (int o = 32; o > 0; o >>= 1) ss += __shfl_xor(ss, o);
  __shared__ float ps[4];
  if ((tid & 63) == 0) ps[tid >> 6] = ss;
  __syncthreads();
  float tot = ps[0] + ps[1] + ps[2] + ps[3];
  float r = rsqrtf(tot * (1.0f / 1024.0f) + 1.1920929e-7f);
  __bf16* xr = x + (size_t)row * 1024 + tid * 4;
  xr[0] = (__bf16)(v.x * r); xr[1] = (__bf16)(v.y * r);
  xr[2] = (__bf16)(v.z * r); xr[3] = (__bf16)(v.w * r);
}

// ---------------- GEMM 128x128 dbuf (plain store) — used for proj ----------
__global__ __launch_bounds__(256) void gemm_bt_k(
    const __bf16* __restrict__ A, const __bf16* __restrict__ Bt,
    float* __restrict__ C, int N, int K) {
  __shared__ __bf16 sA[2][128 * 32];
  __shared__ __bf16 sB[2][128 * 32];
  const int tid = threadIdx.x;
  const int lane = tid & 63;
  const int quad = lane >> 4, l16 = lane & 15;
  const int wave = tid >> 6;
  const int waveM = wave >> 1, waveN = wave & 1;
  const int m0 = blockIdx.y * 128, n0 = blockIdx.x * 128;
  const int nk = K >> 5;
  const int rowS = tid >> 2;
  const int kgS = (tid & 3) * 8;
  const __bf16* gA0 = A + (size_t)(m0 + rowS) * K + kgS;
  const __bf16* gA1 = gA0 + (size_t)64 * K;
  const __bf16* gB0 = Bt + (size_t)(n0 + rowS) * K + kgS;
  const __bf16* gB1 = gB0 + (size_t)64 * K;
  const int lo0 = tid * 8, lo1 = 2048 + tid * 8;

  GLD16(gA0, sA[0] + lo0);
  GLD16(gA1, sA[0] + lo1);
  GLD16(gB0, sB[0] + lo0);
  GLD16(gB1, sB[0] + lo1);

  f32x4 acc[4][4] = {};
  for (int i = 0; i < nk; ++i) {
    __syncthreads();
    if (i + 1 < nk) {
      const int k = (i + 1) * 32;
      __bf16* dA = sA[(i + 1) & 1];
      __bf16* dB = sB[(i + 1) & 1];
      GLD16(gA0 + k, dA + lo0);
      GLD16(gA1 + k, dA + lo1);
      GLD16(gB0 + k, dB + lo0);
      GLD16(gB1 + k, dB + lo1);
    }
    const __bf16* cA = sA[i & 1];
    const __bf16* cB = sB[i & 1];
    bf16x8 af[4], bfv[4];
    #pragma unroll
    for (int mt = 0; mt < 4; ++mt)
      af[mt] = *(const bf16x8*)(cA + (waveM * 64 + mt * 16 + l16) * 32 + quad * 8);
    #pragma unroll
    for (int nt = 0; nt < 4; ++nt)
      bfv[nt] = *(const bf16x8*)(cB + (waveN * 64 + nt * 16 + l16) * 32 + quad * 8);
    #pragma unroll
    for (int mt = 0; mt < 4; ++mt)
      #pragma unroll
      for (int nt = 0; nt < 4; ++nt)
        acc[mt][nt] = __builtin_amdgcn_mfma_f32_16x16x32_bf16(af[mt], bfv[nt], acc[mt][nt], 0, 0, 0);
  }
  #pragma unroll
  for (int mt = 0; mt < 4; ++mt) {
    int row = m0 + waveM * 64 + mt * 16 + quad * 4;
    #pragma unroll
    for (int nt = 0; nt < 4; ++nt) {
      int col = n0 + waveN * 64 + nt * 16 + l16;
      #pragma unroll
      for (int r = 0; r < 4; ++r)
        C[(size_t)(row + r) * N + col] = acc[mt][nt][r];
    }
  }
}

// ---------------- GEMM 128x128 dbuf, split-K to per-slice partial buffers ---
// Partial kz goes to P + kz*M*N (plain stores, no atomics).
__global__ __launch_bounds__(256) void gemm_partk_k(
    const __bf16* __restrict__ A, const __bf16* __restrict__ Bt,
    float* __restrict__ P, int N, int K) {
  __shared__ __bf16 sA[2][128 * 32];
  __shared__ __bf16 sB[2][128 * 32];
  const int tid = threadIdx.x;
  const int lane = tid & 63;
  const int quad = lane >> 4, l16 = lane & 15;
  const int wave = tid >> 6;
  const int waveM = wave >> 1, waveN = wave & 1;
  const int m0 = blockIdx.y * 128, n0 = blockIdx.x * 128;
  const int kz = blockIdx.z, nz = gridDim.z;
  const int kper = K / nz, kbeg = kz * kper;
  const int nk = kper >> 5;
  const size_t MN = (size_t)gridDim.y * 128 * N;
  float* C = P + (size_t)kz * MN;
  const int rowS = tid >> 2;
  const int kgS = (tid & 3) * 8;
  const __bf16* gA0 = A + (size_t)(m0 + rowS) * K + kbeg + kgS;
  const __bf16* gA1 = gA0 + (size_t)64 * K;
  const __bf16* gB0 = Bt + (size_t)(n0 + rowS) * K + kbeg + kgS;
  const __bf16* gB1 = gB0 + (size_t)64 * K;
  const int lo0 = tid * 8, lo1 = 2048 + tid * 8;

  GLD16(gA0, sA[0] + lo0);
  GLD16(gA1, sA[0] + lo1);
  GLD16(gB0, sB[0] + lo0);
  GLD16(gB1, sB[0] + lo1);

  f32x4 acc[4][4] = {};
  for (int i = 0; i < nk; ++i) {
    __syncthreads();
    if (i + 1 < nk) {
      const int k = (i + 1) * 32;
      __bf16* dA = sA[(i + 1) & 1];
      __bf16* dB = sB[(i + 1) & 1];
      GLD16(gA0 + k, dA + lo0);
      GLD16(gA1 + k, dA + lo1);
      GLD16(gB0 + k, dB + lo0);
      GLD16(gB1 + k, dB + lo1);
    }
    const __bf16* cA = sA[i & 1];
    const __bf16* cB = sB[i & 1];
    bf16x8 af[4], bfv[4];
    #pragma unroll
    for (int mt = 0; mt < 4; ++mt)
      af[mt] = *(const bf16x8*)(cA + (waveM * 64 + mt * 16 + l16) * 32 + quad * 8);
    #pragma unroll
    for (int nt = 0; nt < 4; ++nt)
      bfv[nt] = *(const bf16x8*)(cB + (waveN * 64 + nt * 16 + l16) * 32 + quad * 8);
    #pragma unroll
    for (int mt = 0; mt < 4; ++mt)
      #pragma unroll
      for (int nt = 0; nt < 4; ++nt)
        acc[mt][nt] = __builtin_amdgcn_mfma_f32_16x16x32_bf16(af[mt], bfv[nt], acc[mt][nt], 0, 0, 0);
  }
  #pragma unroll
  for (int mt = 0; mt < 4; ++mt) {
    int row = m0 + waveM * 64 + mt * 16 + quad * 4;
    #pragma unroll
    for (int nt = 0; nt < 4; ++nt) {
      int col = n0 + waveN * 64 + nt * 16 + l16;
      #pragma unroll
      for (int r = 0; r < 4; ++r)
        C[(size_t)(row + r) * N + col] = acc[mt][nt][r];
    }
  }
}

// ---------------- fused FFN1 + bias + SwiGLU --------------------------------
// ffin[s][j] = silu(x@W1[:,4096+j] + b1[4096+j]) * (x@W1[:,j] + b1[j]), bf16.
// Tile 128 rows x 64 ffin-cols; block stages A(128x32), Bx(64x32), Bg(64x32).
// grid (64,16) = 1024 blocks -> 3-4 blocks/CU co-resident (latency overlap).
__global__ __launch_bounds__(256) void ffn1silu_k(
    const __bf16* __restrict__ A, const __bf16* __restrict__ W1t,
    const float* __restrict__ b1, __bf16* __restrict__ ffin) {
  __shared__ __bf16 sA[2][128 * 32];
  __shared__ __bf16 sBx[2][64 * 32];
  __shared__ __bf16 sBg[2][64 * 32];
  const int tid = threadIdx.x, lane = tid & 63, w = tid >> 6;
  const int quad = lane >> 4, l16 = lane & 15;
  const int m0 = blockIdx.y * 128, n0 = blockIdx.x * 64;
  const int K = 1024, nk = 32;
  const int rowS = tid >> 2, kgS = (tid & 3) * 8;
  const __bf16* gA0 = A + (size_t)(m0 + rowS) * K + kgS;
  const __bf16* gA1 = gA0 + (size_t)64 * K;
  const __bf16* gBx = W1t + (size_t)(n0 + rowS) * K + kgS;
  const __bf16* gBg = W1t + (size_t)(4096 + n0 + rowS) * K + kgS;
  const int lo = tid * 8;

  GLD16(gA0, sA[0] + lo);
  GLD16(gA1, sA[0] + 2048 + lo);
  GLD16(gBx, sBx[0] + lo);
  GLD16(gBg, sBg[0] + lo);

  f32x4 ax[2][4] = {}, ag[2][4] = {};
  for (int i = 0; i < nk; ++i) {
    __syncthreads();
    if (i + 1 < nk) {
      const int k = (i + 1) * 32, b = (i + 1) & 1;
      GLD16(gA0 + k, sA[b] + lo);
      GLD16(gA1 + k, sA[b] + 2048 + lo);
      GLD16(gBx + k, sBx[b] + lo);
      GLD16(gBg + k, sBg[b] + lo);
    }
    const __bf16* cA = sA[i & 1];
    const __bf16* cx = sBx[i & 1];
    const __bf16* cg = sBg[i & 1];
    bf16x8 af[2], bx[4], bg[4];
    #pragma unroll
    for (int mt = 0; mt < 2; ++mt)
      af[mt] = *(const bf16x8*)(cA + (w * 32 + mt * 16 + l16) * 32 + quad * 8);
    #pragma unroll
    for (int nt = 0; nt < 4; ++nt) {
      bx[nt] = *(const bf16x8*)(cx + (nt * 16 + l16) * 32 + quad * 8);
      bg[nt] = *(const bf16x8*)(cg + (nt * 16 + l16) * 32 + quad * 8);
    }
    #pragma unroll
    for (int mt = 0; mt < 2; ++mt)
      #pragma unroll
      for (int nt = 0; nt < 4; ++nt) {
        ax[mt][nt] = __builtin_amdgcn_mfma_f32_16x16x32_bf16(af[mt], bx[nt], ax[mt][nt], 0, 0, 0);
        ag[mt][nt] = __builtin_amdgcn_mfma_f32_16x16x32_bf16(af[mt], bg[nt], ag[mt][nt], 0, 0, 0);
      }
  }
  #pragma unroll
  for (int mt = 0; mt < 2; ++mt) {
    int row = m0 + w * 32 + mt * 16 + quad * 4;
    #pragma unroll
    for (int nt = 0; nt < 4; ++nt) {
      int col = n0 + nt * 16 + l16;
      float bxv = b1[col], bgv = b1[col + 4096];
      #pragma unroll
      for (int r = 0; r < 4; ++r) {
        float xp = ax[mt][nt][r] + bxv;
        float g  = ag[mt][nt][r] + bgv;
        float val = xp * g / (1.f + __expf(-g));
        ffin[(size_t)(row + r) * 4096 + col] = (__bf16)val;
      }
    }
  }
}

// ---------------- combine: out = Σ4 ffn2_p + b2 + Σ4 wo_p + bo + lam*h -----
__global__ __launch_bounds__(256) void combine_k(
    const float* __restrict__ f2p, const float* __restrict__ wop,
    const float* __restrict__ b2, const float* __restrict__ bo,
    const float* __restrict__ hs, const float* __restrict__ plam,
    float* __restrict__ out) {
  const size_t MN = (size_t)2048 * 1024;
  size_t i = ((size_t)blockIdx.x * 256 + threadIdx.x) * 4;
  int col = (int)(i & 1023);
  float4 a0 = *(const float4*)(f2p + i);
  float4 a1 = *(const float4*)(f2p + MN + i);
  float4 a2 = *(const float4*)(f2p + 2 * MN + i);
  float4 a3 = *(const float4*)(f2p + 3 * MN + i);
  float4 w0 = *(const float4*)(wop + i);
  float4 w1 = *(const float4*)(wop + MN + i);
  float4 w2 = *(const float4*)(wop + 2 * MN + i);
  float4 w3 = *(const float4*)(wop + 3 * MN + i);
  float4 h  = *(const float4*)(hs + i);
  float4 v2 = *(const float4*)(b2 + col);
  float4 vo = *(const float4*)(bo + col);
  float lam = plam[0];
  float4 o;
  o.x = (a0.x + a1.x) + (a2.x + a3.x) + v2.x + (w0.x + w1.x) + (w2.x + w3.x) + vo.x + lam * h.x;
  o.y = (a0.y + a1.y) + (a2.y + a3.y) + v2.y + (w0.y + w1.y) + (w2.y + w3.y) + vo.y + lam * h.y;
  o.z = (a0.z + a1.z) + (a2.z + a3.z) + v2.z + (w0.z + w1.z) + (w2.z + w3.z) + vo.z + lam * h.z;
  o.w = (a0.w + a1.w) + (a2.w + a3.w) + v2.w + (w0.w + w1.w) + (w2.w + w3.w) + vo.w + lam * h.w;
  *(float4*)(out + i) = o;
}

// ---------------- l2norm + RoPE for q,k,qb,kb -------------------------------
__global__ __launch_bounds__(256) void qkprep_k(const float* __restrict__ proj,
    __bf16* __restrict__ qo, __bf16* __restrict__ ko,
    float* __restrict__ qbo, float* __restrict__ kbo) {
  int gw = blockIdx.x * 4 + (threadIdx.x >> 6);
  int lane = threadIdx.x & 63;
  int s = gw >> 4, h = gw & 15;
  int j = lane & 31;
  float inv = powf(1000.0f, -(float)j * (1.0f / 32.0f));
  float ang = (float)s * inv;
  float cb = (float)(__bf16)cosf(ang);
  float sb = (float)(__bf16)sinf(ang);
  size_t ibase = (size_t)s * 5120 + h * 64 + lane;
  size_t obase = (size_t)s * 1024 + h * 64 + lane;
  bool lo = lane < 32;

  auto proc = [&](const float* src) -> float {
    float xv = src[ibase];
    float ss = xv * xv;
    #pragma unroll
    for (int o = 32; o > 0; o >>= 1) ss += __shfl_xor(ss, o);
    float y = xv / fmaxf(sqrtf(ss), 1e-12f);
    float yp = __shfl_xor(y, 32);
    return lo ? (y * cb + yp * sb) : (y * cb - yp * sb);
  };
  qo[obase]  = (__bf16)proc(proj + 0);
  ko[obase]  = (__bf16)proc(proj + 1024);
  qbo[obase] = proc(proj + 3072);
  kbo[obase] = proc(proj + 4096);
}

// ---------------- sb row-sum via two-level cumsum ---------------------------
__global__ __launch_bounds__(64) void kbsum_k(const float* __restrict__ kb,
                                              float* __restrict__ tsum) {
  int t = blockIdx.x, h = blockIdx.y, d = threadIdx.x;
  size_t base = (size_t)h * 64 + d;
  float s = 0.f;
  #pragma unroll 4
  for (int r = 0; r < 32; ++r)
    s += kb[(size_t)(t * 32 + r) * 1024 + base];
  tsum[(t * 16 + h) * 64 + d] = s;
}

__global__ __launch_bounds__(64) void sbrow2_k(const float* __restrict__ qb,
                                               const float* __restrict__ kb,
                                               const float* __restrict__ tsum,
                                               float* __restrict__ sb) {
  int t = blockIdx.x, h = blockIdx.y, d = threadIdx.x;
  size_t base = (size_t)h * 64 + d;
  float run = 0.f;
  for (int tp = 0; tp < t; ++tp) run += tsum[(tp * 16 + h) * 64 + d];
  for (int s0 = 0; s0 < 32; s0 += 4) {
    float p[4];
    #pragma unroll
    for (int u = 0; u < 4; ++u) {
      size_t off = (size_t)(t * 32 + s0 + u) * 1024 + base;
      run += kb[off];
      p[u] = qb[off] * run;
    }
    #pragma unroll
    for (int o = 32; o > 0; o >>= 1) {
      #pragma unroll
      for (int u = 0; u < 4; ++u) p[u] += __shfl_xor(p[u], o);
    }
    if (d == 0) {
      #pragma unroll
      for (int u = 0; u < 4; ++u) sb[(t * 32 + s0 + u) * 16 + h] = 0.125f * p[u];
    }
  }
}

// ---------------- flash attention: register softmax, balanced pairing -------
__global__ __launch_bounds__(256) void attn_k(const __bf16* __restrict__ qg,
    const __bf16* __restrict__ kg, const __bf16* __restrict__ vtg,
    const float* __restrict__ sbr, const float* __restrict__ pl2s,
    __bf16* __restrict__ yo) {
  __shared__ __bf16 sK[64 * 64];
  __shared__ __bf16 sVt[64 * 64];
  __shared__ __bf16 sP[64 * 72];
  const int pair = blockIdx.x, hh = blockIdx.y;
  const int tid = threadIdx.x, lane = tid & 63, w = tid >> 6;
  const int quad = lane >> 4, l16 = lane & 15;
  const float l2s = pl2s[0];
  const int rS = tid >> 3, cS = (tid & 7) * 8;
  __bf16* ldsK = sK + tid * 8;
  __bf16* ldsV = sVt + tid * 8;

  for (int phase = 0; phase < 2; ++phase) {
    const int qt = (phase == 0) ? pair : 31 - pair;
    const int q0 = qt * 64;
    bf16x8 qf[2];
    #pragma unroll
    for (int kk = 0; kk < 2; ++kk)
      qf[kk] = *(const bf16x8*)(qg + (size_t)(q0 + w * 16 + l16) * 1024 + hh * 64 + kk * 32 + quad * 8);
    f32x4 accO[4] = {};
    float m_[4], l_[4];
    #pragma unroll
    for (int r = 0; r < 4; ++r) { m_[r] = -INFINITY; l_[r] = 0.f; }

    for (int kt = 0; kt <= qt; ++kt) {
      const __bf16* gK = kg + (size_t)(kt * 64 + rS) * 1024 + hh * 64 + cS;
      const __bf16* gV = vtg + (size_t)(hh * 64 + rS) * 2048 + kt * 64 + cS;
      GLD16(gK, ldsK);
      GLD16(gK + (size_t)32 * 1024, ldsK + 2048);
      GLD16(gV, ldsV);
      GLD16(gV + (size_t)32 * 2048, ldsV + 2048);
      __syncthreads();

      f32x4 s4[4];
      #pragma unroll
      for (int nt = 0; nt < 4; ++nt) {
        bf16x8 b0 = *(const bf16x8*)(sK + (nt * 16 + l16) * 64 + quad * 8);
        bf16x8 b1 = *(const bf16x8*)(sK + (nt * 16 + l16) * 64 + 32 + quad * 8);
        f32x4 sa = {0.f, 0.f, 0.f, 0.f};
        sa = __builtin_amdgcn_mfma_f32_16x16x32_bf16(qf[0], b0, sa, 0, 0, 0);
        sa = __builtin_amdgcn_mfma_f32_16x16x32_bf16(qf[1], b1, sa, 0, 0, 0);
        s4[nt] = sa;
      }
      if (kt == qt) {
        #pragma unroll
        for (int nt = 0; nt < 4; ++nt)
          #pragma unroll
          for (int r = 0; r < 4; ++r)
            if (nt * 16 + l16 > w * 16 + quad * 4 + r) s4[nt][r] = -INFINITY;
      }
      float mx[4], al[4], rs[4];
      #pragma unroll
      for (int r = 0; r < 4; ++r)
        mx[r] = fmaxf(fmaxf(s4[0][r], s4[1][r]), fmaxf(s4[2][r], s4[3][r]));
      #pragma unroll
      for (int o = 1; o < 16; o <<= 1)
        #pragma unroll
        for (int r = 0; r < 4; ++r) mx[r] = fmaxf(mx[r], __shfl_xor(mx[r], o));
      #pragma unroll
      for (int r = 0; r < 4; ++r) {
        float mn = fmaxf(m_[r], mx[r]);
        al[r] = __expf(m_[r] - mn);
        m_[r] = mn;
      }
      float p[4][4];
      #pragma unroll
      for (int nt = 0; nt < 4; ++nt)
        #pragma unroll
        for (int r = 0; r < 4; ++r)
          p[nt][r] = __expf(s4[nt][r] - m_[r]);
      #pragma unroll
      for (int r = 0; r < 4; ++r)
        rs[r] = (p[0][r] + p[1][r]) + (p[2][r] + p[3][r]);
      #pragma unroll
      for (int o = 1; o < 16; o <<= 1)
        #pragma unroll
        for (int r = 0; r < 4; ++r) rs[r] += __shfl_xor(rs[r], o);
      #pragma unroll
      for (int r = 0; r < 4; ++r) l_[r] = l_[r] * al[r] + rs[r];
      #pragma unroll
      for (int nt = 0; nt < 4; ++nt)
        #pragma unroll
        for (int r = 0; r < 4; ++r) accO[nt][r] *= al[r];
      #pragma unroll
      for (int nt = 0; nt < 4; ++nt)
        #pragma unroll
        for (int r = 0; r < 4; ++r)
          sP[(w * 16 + quad * 4 + r) * 72 + nt * 16 + l16] = (__bf16)p[nt][r];
      #pragma unroll
      for (int kk = 0; kk < 2; ++kk) {
        bf16x8 a = *(const bf16x8*)(sP + (w * 16 + l16) * 72 + kk * 32 + quad * 8);
        #pragma unroll
        for (int nt = 0; nt < 4; ++nt) {
          bf16x8 bv = *(const bf16x8*)(sVt + (nt * 16 + l16) * 64 + kk * 32 + quad * 8);
          accO[nt] = __builtin_amdgcn_mfma_f32_16x16x32_bf16(a, bv, accO[nt], 0, 0, 0);
        }
      }
      __syncthreads();
    }
    #pragma unroll
    for (int nt = 0; nt < 4; ++nt) {
      int dcol = nt * 16 + l16;
      #pragma unroll
      for (int r = 0; r < 4; ++r) {
        int grow = q0 + w * 16 + quad * 4 + r;
        float val = l2s * accO[nt][r] / l_[r] + sbr[grow * 16 + hh];
        yo[(size_t)grow * 1024 + hh * 64 + dcol] = (__bf16)val;
      }
    }
  }
}

extern "C" void kernel_launch(void* const* d_in, const int* in_sizes, int n_in,
                              void* d_out, int out_size, void* d_ws, size_t ws_size,
                              hipStream_t stream) {
  (void)in_sizes; (void)n_in; (void)out_size; (void)ws_size;
  const float* hs   = (const float*)d_in[0];
  const float* Wq   = (const float*)d_in[1];
  const float* Wk   = (const float*)d_in[2];
  const float* Wv   = (const float*)d_in[3];
  const float* Wqb  = (const float*)d_in[4];
  const float* Wkb  = (const float*)d_in[5];
  const float* Wo   = (const float*)d_in[6];
  const float* bo   = (const float*)d_in[7];
  const float* W1   = (const float*)d_in[8];
  const float* b1   = (const float*)d_in[9];
  const float* W2   = (const float*)d_in[10];
  const float* b2   = (const float*)d_in[11];
  const float* plam = (const float*)d_in[12];
  const float* pl2s = (const float*)d_in[13];
  float* out = (float*)d_out;
  char* ws = (char*)d_ws;

  size_t off = 0;
  auto alloc = [&](size_t bytes) { char* p = ws + off; off += (bytes + 255) & ~(size_t)255; return p; };
  __bf16* Wt5  = (__bf16*)alloc((size_t)5 * 1024 * 1024 * 2);
  __bf16* Wot  = (__bf16*)alloc((size_t)1024 * 1024 * 2);
  __bf16* W1t  = (__bf16*)alloc((size_t)8192 * 1024 * 2);
  __bf16* W2t  = (__bf16*)alloc((size_t)1024 * 4096 * 2);
  __bf16* xbf  = (__bf16*)alloc((size_t)2048 * 1024 * 2);
  // 64 MB region: [proj 40 | qbf32 8 | kbf32 8 | qbf 4 | kbf 4] — all dead
  // after attn_k; wo_part (32 MB) aliases the front, f2_part (32 MB) the back.
  float*  proj  = (float*)alloc((size_t)2048 * 5120 * 4);
  float*  qbf32 = (float*)alloc((size_t)2048 * 1024 * 4);
  float*  kbf32 = (float*)alloc((size_t)2048 * 1024 * 4);
  __bf16* qbf   = (__bf16*)alloc((size_t)2048 * 1024 * 2);
  __bf16* kbf   = (__bf16*)alloc((size_t)2048 * 1024 * 2);
  float*  wo_part = proj;                                   // 4 x 8 MB
  float*  f2_part = (float*)((char*)proj + (size_t)32 * 1024 * 1024);  // 4 x 8 MB
  __bf16* vtbf  = (__bf16*)alloc((size_t)1024 * 2048 * 2);
  __bf16* ybf   = (__bf16*)alloc((size_t)2048 * 1024 * 2);
  float*  sbrow = (float*)alloc((size_t)2048 * 16 * 4);
  float*  tsum  = (float*)alloc((size_t)64 * 16 * 64 * 4);
  __bf16* ffin  = (__bf16*)alloc((size_t)2048 * 4096 * 2);

  tconv_k<<<dim3(32, 32), 256, 0, stream>>>(Wq,  Wt5,               1024, 1024);
  tconv_k<<<dim3(32, 32), 256, 0, stream>>>(Wk,  Wt5 + 1048576,     1024, 1024);
  tconv_k<<<dim3(32, 32), 256, 0, stream>>>(Wv,  Wt5 + 2 * 1048576, 1024, 1024);
  tconv_k<<<dim3(32, 32), 256, 0, stream>>>(Wqb, Wt5 + 3 * 1048576, 1024, 1024);
  tconv_k<<<dim3(32, 32), 256, 0, stream>>>(Wkb, Wt5 + 4 * 1048576, 1024, 1024);
  tconv_k<<<dim3(32, 32), 256, 0, stream>>>(Wo,  Wot,               1024, 1024);
  tconv_k<<<dim3(256, 32), 256, 0, stream>>>(W1, W1t,               8192, 1024);
  tconv_k<<<dim3(32, 128), 256, 0, stream>>>(W2, W2t,               1024, 4096);

  rmsnorm_k<<<2048, 256, 0, stream>>>(hs, xbf);
  gemm_bt_k<<<dim3(40, 16), 256, 0, stream>>>(xbf, Wt5, proj, 5120, 1024);
  qkprep_k<<<8192, 256, 0, stream>>>(proj, qbf, kbf, qbf32, kbf32);
  tconv_k<<<dim3(32, 64), 256, 0, stream>>>(proj + 2048, vtbf, 5120, 2048);
  kbsum_k<<<dim3(64, 16), 64, 0, stream>>>(kbf32, tsum);
  sbrow2_k<<<dim3(64, 16), 64, 0, stream>>>(qbf32, kbf32, tsum, sbrow);
  attn_k<<<dim3(16, 16), 256, 0, stream>>>(qbf, kbf, vtbf, sbrow, pl2s, ybf);
  // Wo partials: y @ Wo, split-K x4 (proj region now dead)
  gemm_partk_k<<<dim3(8, 16, 4), 256, 0, stream>>>(ybf, Wot, wo_part, 1024, 1024);
  // fused FFN1 + bias + SwiGLU -> ffin (bf16)
  ffn1silu_k<<<dim3(64, 16), 256, 0, stream>>>(xbf, W1t, b1, ffin);
  // FFN2 partials: ffin @ W2, split-K x4
  gemm_partk_k<<<dim3(8, 16, 4), 256, 0, stream>>>(ffin, W2t, f2_part, 1024, 4096);
  // out = Σ f2_part + b2 + Σ wo_part + bo + lam*h
  combine_k<<<2048, 256, 0, stream>>>(f2_part, wo_part, b2, bo, hs, plam, out);
}

// Round 6
// 410.347 us; speedup vs baseline: 1.2436x; 1.0382x over previous
//
#include <hip/hip_runtime.h>
#include <hip/hip_bf16.h>
#include <math.h>

typedef __bf16 bf16x8 __attribute__((ext_vector_type(8)));
typedef float  f32x4  __attribute__((ext_vector_type(4)));

#define GLD16(g, l) __builtin_amdgcn_global_load_lds(                      \
    (const __attribute__((address_space(1))) void*)(g),                    \
    (__attribute__((address_space(3))) void*)(l), 16, 0, 0)

// ---------------- transpose + f32 -> bf16 convert (out[c][r] = in[r][c]) ----
__global__ __launch_bounds__(256) void tconv_k(const float* __restrict__ in,
                                               __bf16* __restrict__ out,
                                               int ldin, int ldout) {
  __shared__ float t[32][33];
  int c0 = blockIdx.x * 32, r0 = blockIdx.y * 32;
  int tx = threadIdx.x & 31, ty = threadIdx.x >> 5;
  #pragma unroll
  for (int i = ty; i < 32; i += 8)
    t[i][tx] = in[(size_t)(r0 + i) * ldin + c0 + tx];
  __syncthreads();
  #pragma unroll
  for (int i = ty; i < 32; i += 8)
    out[(size_t)(c0 + i) * ldout + r0 + tx] = (__bf16)t[tx][i];
}

// ---------------- RMSNorm ---------------------------------------------------
__global__ __launch_bounds__(256) void rmsnorm_k(const float* __restrict__ hs,
                                                 __bf16* __restrict__ x) {
  int row = blockIdx.x, tid = threadIdx.x;
  const float4 v = ((const float4*)(hs + (size_t)row * 1024))[tid];
  float ss = v.x * v.x + v.y * v.y + v.z * v.z + v.w * v.w;
  #pragma unroll
  for (int o = 32; o > 0; o >>= 1) ss += __shfl_xor(ss, o);
  __shared__ float ps[4];
  if ((tid & 63) == 0) ps[tid >> 6] = ss;
  __syncthreads();
  float tot = ps[0] + ps[1] + ps[2] + ps[3];
  float r = rsqrtf(tot * (1.0f / 1024.0f) + 1.1920929e-7f);
  __bf16* xr = x + (size_t)row * 1024 + tid * 4;
  xr[0] = (__bf16)(v.x * r); xr[1] = (__bf16)(v.y * r);
  xr[2] = (__bf16)(v.z * r); xr[3] = (__bf16)(v.w * r);
}

// ---------------- GEMM 128x128 dbuf (plain store) — used for proj ----------
__global__ __launch_bounds__(256) void gemm_bt_k(
    const __bf16* __restrict__ A, const __bf16* __restrict__ Bt,
    float* __restrict__ C, int N, int K) {
  __shared__ __bf16 sA[2][128 * 32];
  __shared__ __bf16 sB[2][128 * 32];
  const int tid = threadIdx.x;
  const int lane = tid & 63;
  const int quad = lane >> 4, l16 = lane & 15;
  const int wave = tid >> 6;
  const int waveM = wave >> 1, waveN = wave & 1;
  const int m0 = blockIdx.y * 128, n0 = blockIdx.x * 128;
  const int nk = K >> 5;
  const int rowS = tid >> 2;
  const int kgS = (tid & 3) * 8;
  const __bf16* gA0 = A + (size_t)(m0 + rowS) * K + kgS;
  const __bf16* gA1 = gA0 + (size_t)64 * K;
  const __bf16* gB0 = Bt + (size_t)(n0 + rowS) * K + kgS;
  const __bf16* gB1 = gB0 + (size_t)64 * K;
  const int lo0 = tid * 8, lo1 = 2048 + tid * 8;

  GLD16(gA0, sA[0] + lo0);
  GLD16(gA1, sA[0] + lo1);
  GLD16(gB0, sB[0] + lo0);
  GLD16(gB1, sB[0] + lo1);

  f32x4 acc[4][4] = {};
  for (int i = 0; i < nk; ++i) {
    __syncthreads();
    if (i + 1 < nk) {
      const int k = (i + 1) * 32;
      __bf16* dA = sA[(i + 1) & 1];
      __bf16* dB = sB[(i + 1) & 1];
      GLD16(gA0 + k, dA + lo0);
      GLD16(gA1 + k, dA + lo1);
      GLD16(gB0 + k, dB + lo0);
      GLD16(gB1 + k, dB + lo1);
    }
    const __bf16* cA = sA[i & 1];
    const __bf16* cB = sB[i & 1];
    bf16x8 af[4], bfv[4];
    #pragma unroll
    for (int mt = 0; mt < 4; ++mt)
      af[mt] = *(const bf16x8*)(cA + (waveM * 64 + mt * 16 + l16) * 32 + quad * 8);
    #pragma unroll
    for (int nt = 0; nt < 4; ++nt)
      bfv[nt] = *(const bf16x8*)(cB + (waveN * 64 + nt * 16 + l16) * 32 + quad * 8);
    #pragma unroll
    for (int mt = 0; mt < 4; ++mt)
      #pragma unroll
      for (int nt = 0; nt < 4; ++nt)
        acc[mt][nt] = __builtin_amdgcn_mfma_f32_16x16x32_bf16(af[mt], bfv[nt], acc[mt][nt], 0, 0, 0);
  }
  #pragma unroll
  for (int mt = 0; mt < 4; ++mt) {
    int row = m0 + waveM * 64 + mt * 16 + quad * 4;
    #pragma unroll
    for (int nt = 0; nt < 4; ++nt) {
      int col = n0 + waveN * 64 + nt * 16 + l16;
      #pragma unroll
      for (int r = 0; r < 4; ++r)
        C[(size_t)(row + r) * N + col] = acc[mt][nt][r];
    }
  }
}

// ---------------- GEMM 128x128 dbuf, split-K to per-slice partial buffers ---
__global__ __launch_bounds__(256) void gemm_partk_k(
    const __bf16* __restrict__ A, const __bf16* __restrict__ Bt,
    float* __restrict__ P, int N, int K) {
  __shared__ __bf16 sA[2][128 * 32];
  __shared__ __bf16 sB[2][128 * 32];
  const int tid = threadIdx.x;
  const int lane = tid & 63;
  const int quad = lane >> 4, l16 = lane & 15;
  const int wave = tid >> 6;
  const int waveM = wave >> 1, waveN = wave & 1;
  const int m0 = blockIdx.y * 128, n0 = blockIdx.x * 128;
  const int kz = blockIdx.z, nz = gridDim.z;
  const int kper = K / nz, kbeg = kz * kper;
  const int nk = kper >> 5;
  const size_t MN = (size_t)gridDim.y * 128 * N;
  float* C = P + (size_t)kz * MN;
  const int rowS = tid >> 2;
  const int kgS = (tid & 3) * 8;
  const __bf16* gA0 = A + (size_t)(m0 + rowS) * K + kbeg + kgS;
  const __bf16* gA1 = gA0 + (size_t)64 * K;
  const __bf16* gB0 = Bt + (size_t)(n0 + rowS) * K + kbeg + kgS;
  const __bf16* gB1 = gB0 + (size_t)64 * K;
  const int lo0 = tid * 8, lo1 = 2048 + tid * 8;

  GLD16(gA0, sA[0] + lo0);
  GLD16(gA1, sA[0] + lo1);
  GLD16(gB0, sB[0] + lo0);
  GLD16(gB1, sB[0] + lo1);

  f32x4 acc[4][4] = {};
  for (int i = 0; i < nk; ++i) {
    __syncthreads();
    if (i + 1 < nk) {
      const int k = (i + 1) * 32;
      __bf16* dA = sA[(i + 1) & 1];
      __bf16* dB = sB[(i + 1) & 1];
      GLD16(gA0 + k, dA + lo0);
      GLD16(gA1 + k, dA + lo1);
      GLD16(gB0 + k, dB + lo0);
      GLD16(gB1 + k, dB + lo1);
    }
    const __bf16* cA = sA[i & 1];
    const __bf16* cB = sB[i & 1];
    bf16x8 af[4], bfv[4];
    #pragma unroll
    for (int mt = 0; mt < 4; ++mt)
      af[mt] = *(const bf16x8*)(cA + (waveM * 64 + mt * 16 + l16) * 32 + quad * 8);
    #pragma unroll
    for (int nt = 0; nt < 4; ++nt)
      bfv[nt] = *(const bf16x8*)(cB + (waveN * 64 + nt * 16 + l16) * 32 + quad * 8);
    #pragma unroll
    for (int mt = 0; mt < 4; ++mt)
      #pragma unroll
      for (int nt = 0; nt < 4; ++nt)
        acc[mt][nt] = __builtin_amdgcn_mfma_f32_16x16x32_bf16(af[mt], bfv[nt], acc[mt][nt], 0, 0, 0);
  }
  #pragma unroll
  for (int mt = 0; mt < 4; ++mt) {
    int row = m0 + waveM * 64 + mt * 16 + quad * 4;
    #pragma unroll
    for (int nt = 0; nt < 4; ++nt) {
      int col = n0 + waveN * 64 + nt * 16 + l16;
      #pragma unroll
      for (int r = 0; r < 4; ++r)
        C[(size_t)(row + r) * N + col] = acc[mt][nt][r];
    }
  }
}

// ---------------- fused FFN1 + bias + SwiGLU --------------------------------
__global__ __launch_bounds__(256) void ffn1silu_k(
    const __bf16* __restrict__ A, const __bf16* __restrict__ W1t,
    const float* __restrict__ b1, __bf16* __restrict__ ffin) {
  __shared__ __bf16 sA[2][128 * 32];
  __shared__ __bf16 sBx[2][64 * 32];
  __shared__ __bf16 sBg[2][64 * 32];
  const int tid = threadIdx.x, lane = tid & 63, w = tid >> 6;
  const int quad = lane >> 4, l16 = lane & 15;
  const int m0 = blockIdx.y * 128, n0 = blockIdx.x * 64;
  const int K = 1024, nk = 32;
  const int rowS = tid >> 2, kgS = (tid & 3) * 8;
  const __bf16* gA0 = A + (size_t)(m0 + rowS) * K + kgS;
  const __bf16* gA1 = gA0 + (size_t)64 * K;
  const __bf16* gBx = W1t + (size_t)(n0 + rowS) * K + kgS;
  const __bf16* gBg = W1t + (size_t)(4096 + n0 + rowS) * K + kgS;
  const int lo = tid * 8;

  GLD16(gA0, sA[0] + lo);
  GLD16(gA1, sA[0] + 2048 + lo);
  GLD16(gBx, sBx[0] + lo);
  GLD16(gBg, sBg[0] + lo);

  f32x4 ax[2][4] = {}, ag[2][4] = {};
  for (int i = 0; i < nk; ++i) {
    __syncthreads();
    if (i + 1 < nk) {
      const int k = (i + 1) * 32, b = (i + 1) & 1;
      GLD16(gA0 + k, sA[b] + lo);
      GLD16(gA1 + k, sA[b] + 2048 + lo);
      GLD16(gBx + k, sBx[b] + lo);
      GLD16(gBg + k, sBg[b] + lo);
    }
    const __bf16* cA = sA[i & 1];
    const __bf16* cx = sBx[i & 1];
    const __bf16* cg = sBg[i & 1];
    bf16x8 af[2], bx[4], bg[4];
    #pragma unroll
    for (int mt = 0; mt < 2; ++mt)
      af[mt] = *(const bf16x8*)(cA + (w * 32 + mt * 16 + l16) * 32 + quad * 8);
    #pragma unroll
    for (int nt = 0; nt < 4; ++nt) {
      bx[nt] = *(const bf16x8*)(cx + (nt * 16 + l16) * 32 + quad * 8);
      bg[nt] = *(const bf16x8*)(cg + (nt * 16 + l16) * 32 + quad * 8);
    }
    #pragma unroll
    for (int mt = 0; mt < 2; ++mt)
      #pragma unroll
      for (int nt = 0; nt < 4; ++nt) {
        ax[mt][nt] = __builtin_amdgcn_mfma_f32_16x16x32_bf16(af[mt], bx[nt], ax[mt][nt], 0, 0, 0);
        ag[mt][nt] = __builtin_amdgcn_mfma_f32_16x16x32_bf16(af[mt], bg[nt], ag[mt][nt], 0, 0, 0);
      }
  }
  #pragma unroll
  for (int mt = 0; mt < 2; ++mt) {
    int row = m0 + w * 32 + mt * 16 + quad * 4;
    #pragma unroll
    for (int nt = 0; nt < 4; ++nt) {
      int col = n0 + nt * 16 + l16;
      float bxv = b1[col], bgv = b1[col + 4096];
      #pragma unroll
      for (int r = 0; r < 4; ++r) {
        float xp = ax[mt][nt][r] + bxv;
        float g  = ag[mt][nt][r] + bgv;
        float val = xp * g / (1.f + __expf(-g));
        ffin[(size_t)(row + r) * 4096 + col] = (__bf16)val;
      }
    }
  }
}

// ---------------- combine: out = Σ4 ffn2_p + b2 + Σ4 wo_p + bo + lam*h -----
__global__ __launch_bounds__(256) void combine_k(
    const float* __restrict__ f2p, const float* __restrict__ wop,
    const float* __restrict__ b2, const float* __restrict__ bo,
    const float* __restrict__ hs, const float* __restrict__ plam,
    float* __restrict__ out) {
  const size_t MN = (size_t)2048 * 1024;
  size_t i = ((size_t)blockIdx.x * 256 + threadIdx.x) * 4;
  int col = (int)(i & 1023);
  float4 a0 = *(const float4*)(f2p + i);
  float4 a1 = *(const float4*)(f2p + MN + i);
  float4 a2 = *(const float4*)(f2p + 2 * MN + i);
  float4 a3 = *(const float4*)(f2p + 3 * MN + i);
  float4 w0 = *(const float4*)(wop + i);
  float4 w1 = *(const float4*)(wop + MN + i);
  float4 w2 = *(const float4*)(wop + 2 * MN + i);
  float4 w3 = *(const float4*)(wop + 3 * MN + i);
  float4 h  = *(const float4*)(hs + i);
  float4 v2 = *(const float4*)(b2 + col);
  float4 vo = *(const float4*)(bo + col);
  float lam = plam[0];
  float4 o;
  o.x = (a0.x + a1.x) + (a2.x + a3.x) + v2.x + (w0.x + w1.x) + (w2.x + w3.x) + vo.x + lam * h.x;
  o.y = (a0.y + a1.y) + (a2.y + a3.y) + v2.y + (w0.y + w1.y) + (w2.y + w3.y) + vo.y + lam * h.y;
  o.z = (a0.z + a1.z) + (a2.z + a3.z) + v2.z + (w0.z + w1.z) + (w2.z + w3.z) + vo.z + lam * h.z;
  o.w = (a0.w + a1.w) + (a2.w + a3.w) + v2.w + (w0.w + w1.w) + (w2.w + w3.w) + vo.w + lam * h.w;
  *(float4*)(out + i) = o;
}

// ---------------- l2norm + RoPE for q,k,qb,kb -------------------------------
__global__ __launch_bounds__(256) void qkprep_k(const float* __restrict__ proj,
    __bf16* __restrict__ qo, __bf16* __restrict__ ko,
    float* __restrict__ qbo, float* __restrict__ kbo) {
  int gw = blockIdx.x * 4 + (threadIdx.x >> 6);
  int lane = threadIdx.x & 63;
  int s = gw >> 4, h = gw & 15;
  int j = lane & 31;
  float inv = powf(1000.0f, -(float)j * (1.0f / 32.0f));
  float ang = (float)s * inv;
  float cb = (float)(__bf16)cosf(ang);
  float sb = (float)(__bf16)sinf(ang);
  size_t ibase = (size_t)s * 5120 + h * 64 + lane;
  size_t obase = (size_t)s * 1024 + h * 64 + lane;
  bool lo = lane < 32;

  auto proc = [&](const float* src) -> float {
    float xv = src[ibase];
    float ss = xv * xv;
    #pragma unroll
    for (int o = 32; o > 0; o >>= 1) ss += __shfl_xor(ss, o);
    float y = xv / fmaxf(sqrtf(ss), 1e-12f);
    float yp = __shfl_xor(y, 32);
    return lo ? (y * cb + yp * sb) : (y * cb - yp * sb);
  };
  qo[obase]  = (__bf16)proc(proj + 0);
  ko[obase]  = (__bf16)proc(proj + 1024);
  qbo[obase] = proc(proj + 3072);
  kbo[obase] = proc(proj + 4096);
}

// ---------------- sb row-sum via two-level cumsum ---------------------------
__global__ __launch_bounds__(64) void kbsum_k(const float* __restrict__ kb,
                                              float* __restrict__ tsum) {
  int t = blockIdx.x, h = blockIdx.y, d = threadIdx.x;
  size_t base = (size_t)h * 64 + d;
  float s = 0.f;
  #pragma unroll 4
  for (int r = 0; r < 32; ++r)
    s += kb[(size_t)(t * 32 + r) * 1024 + base];
  tsum[(t * 16 + h) * 64 + d] = s;
}

__global__ __launch_bounds__(64) void sbrow2_k(const float* __restrict__ qb,
                                               const float* __restrict__ kb,
                                               const float* __restrict__ tsum,
                                               float* __restrict__ sb) {
  int t = blockIdx.x, h = blockIdx.y, d = threadIdx.x;
  size_t base = (size_t)h * 64 + d;
  float run = 0.f;
  for (int tp = 0; tp < t; ++tp) run += tsum[(tp * 16 + h) * 64 + d];
  for (int s0 = 0; s0 < 32; s0 += 4) {
    float p[4];
    #pragma unroll
    for (int u = 0; u < 4; ++u) {
      size_t off = (size_t)(t * 32 + s0 + u) * 1024 + base;
      run += kb[off];
      p[u] = qb[off] * run;
    }
    #pragma unroll
    for (int o = 32; o > 0; o >>= 1) {
      #pragma unroll
      for (int u = 0; u < 4; ++u) p[u] += __shfl_xor(p[u], o);
    }
    if (d == 0) {
      #pragma unroll
      for (int u = 0; u < 4; ++u) sb[(t * 32 + s0 + u) * 16 + h] = 0.125f * p[u];
    }
  }
}

// ---------------- flash attention v3: split-KV x4, swizzled LDS -------------
// Block (pair, quarter j, head). Phase 0: qt=pair, phase 1: qt=31-pair; each
// block covers quarter j of the kt range -> ~9 kt-iters per block, 1024 equal
// blocks = 4 blocks/CU co-resident. LDS rows are XOR-swizzled (group^row&7)
// so all ds_read_b128 are 2-way (free); the swizzle is applied to the GLOBAL
// source address of global_load_lds (its LDS dest is fixed uniform+lane*16).
// Emits unnormalized partials (m, l, O) merged by attnmerge_k.
__global__ __launch_bounds__(256) void attn_k(const __bf16* __restrict__ qg,
    const __bf16* __restrict__ kg, const __bf16* __restrict__ vtg,
    float* __restrict__ o_part, float* __restrict__ m_part,
    float* __restrict__ l_part) {
  __shared__ __bf16 sK[64 * 64];
  __shared__ __bf16 sVt[64 * 64];
  __shared__ __bf16 sP[4][16 * 64];
  const int pair = blockIdx.x, j4 = blockIdx.y, hh = blockIdx.z;
  const int tid = threadIdx.x, lane = tid & 63, w = tid >> 6;
  const int quad = lane >> 4, l16 = lane & 15;
  // staging: thread slot = (row srow, group tid&7); swizzled source group
  const int srow = tid >> 3;
  const int sg = (tid & 7) ^ (srow & 7);
  __bf16* ldsK = sK + tid * 8;
  __bf16* ldsV = sVt + tid * 8;
  __bf16* sPw = sP[w];

  for (int phase = 0; phase < 2; ++phase) {
    const int qt = phase ? 31 - pair : pair;
    const int q0 = qt * 64;
    const int n = qt + 1;
    const int kb = (j4 * n) >> 2, ke = ((j4 + 1) * n) >> 2;
    bf16x8 qf[2];
    #pragma unroll
    for (int kk = 0; kk < 2; ++kk)
      qf[kk] = *(const bf16x8*)(qg + (size_t)(q0 + w * 16 + l16) * 1024 + hh * 64 + kk * 32 + quad * 8);
    f32x4 accO[4] = {};
    float m_[4], l_[4];
    #pragma unroll
    for (int r = 0; r < 4; ++r) { m_[r] = -INFINITY; l_[r] = 0.f; }

    for (int kt = kb; kt < ke; ++kt) {
      const __bf16* gK = kg + (size_t)(kt * 64 + srow) * 1024 + hh * 64 + sg * 8;
      const __bf16* gV = vtg + (size_t)(hh * 64 + srow) * 2048 + kt * 64 + sg * 8;
      GLD16(gK, ldsK);
      GLD16(gK + (size_t)32 * 1024, ldsK + 2048);
      GLD16(gV, ldsV);
      GLD16(gV + (size_t)32 * 2048, ldsV + 2048);
      __syncthreads();

      f32x4 s4[4];
      #pragma unroll
      for (int nt = 0; nt < 4; ++nt) {
        int r = nt * 16 + l16;
        bf16x8 b0 = *(const bf16x8*)(sK + r * 64 + ((quad ^ (r & 7)) * 8));
        bf16x8 b1 = *(const bf16x8*)(sK + r * 64 + (((4 + quad) ^ (r & 7)) * 8));
        f32x4 sa = {0.f, 0.f, 0.f, 0.f};
        sa = __builtin_amdgcn_mfma_f32_16x16x32_bf16(qf[0], b0, sa, 0, 0, 0);
        sa = __builtin_amdgcn_mfma_f32_16x16x32_bf16(qf[1], b1, sa, 0, 0, 0);
        s4[nt] = sa;
      }
      if (kt == qt) {
        #pragma unroll
        for (int nt = 0; nt < 4; ++nt)
          #pragma unroll
          for (int r = 0; r < 4; ++r)
            if (nt * 16 + l16 > w * 16 + quad * 4 + r) s4[nt][r] = -INFINITY;
      }
      float mx[4], al[4], rs[4];
      #pragma unroll
      for (int r = 0; r < 4; ++r)
        mx[r] = fmaxf(fmaxf(s4[0][r], s4[1][r]), fmaxf(s4[2][r], s4[3][r]));
      #pragma unroll
      for (int o = 1; o < 16; o <<= 1)
        #pragma unroll
        for (int r = 0; r < 4; ++r) mx[r] = fmaxf(mx[r], __shfl_xor(mx[r], o));
      #pragma unroll
      for (int r = 0; r < 4; ++r) {
        float mn = fmaxf(m_[r], mx[r]);
        al[r] = __expf(m_[r] - mn);
        m_[r] = mn;
      }
      float p[4][4];
      #pragma unroll
      for (int nt = 0; nt < 4; ++nt)
        #pragma unroll
        for (int r = 0; r < 4; ++r)
          p[nt][r] = __expf(s4[nt][r] - m_[r]);
      #pragma unroll
      for (int r = 0; r < 4; ++r)
        rs[r] = (p[0][r] + p[1][r]) + (p[2][r] + p[3][r]);
      #pragma unroll
      for (int o = 1; o < 16; o <<= 1)
        #pragma unroll
        for (int r = 0; r < 4; ++r) rs[r] += __shfl_xor(rs[r], o);
      #pragma unroll
      for (int r = 0; r < 4; ++r) l_[r] = l_[r] * al[r] + rs[r];
      #pragma unroll
      for (int nt = 0; nt < 4; ++nt)
        #pragma unroll
        for (int r = 0; r < 4; ++r) accO[nt][r] *= al[r];
      // P -> per-wave swizzled LDS (same-wave write/read: no barrier needed)
      #pragma unroll
      for (int nt = 0; nt < 4; ++nt)
        #pragma unroll
        for (int r = 0; r < 4; ++r) {
          int row = quad * 4 + r, col = nt * 16 + l16;
          sPw[row * 64 + (col ^ ((row & 7) << 3))] = (__bf16)p[nt][r];
        }
      #pragma unroll
      for (int kk = 0; kk < 2; ++kk) {
        bf16x8 a = *(const bf16x8*)(sPw + l16 * 64 + (((kk * 4 + quad) ^ (l16 & 7)) * 8));
        #pragma unroll
        for (int nt = 0; nt < 4; ++nt) {
          int vr = nt * 16 + l16;
          bf16x8 bv = *(const bf16x8*)(sVt + vr * 64 + (((kk * 4 + quad) ^ (vr & 7)) * 8));
          accO[nt] = __builtin_amdgcn_mfma_f32_16x16x32_bf16(a, bv, accO[nt], 0, 0, 0);
        }
      }
      __syncthreads();
    }
    // partial epilogue (unnormalized)
    #pragma unroll
    for (int r = 0; r < 4; ++r) {
      int grow = q0 + w * 16 + quad * 4 + r;
      if (l16 == 0) {
        m_part[((size_t)j4 * 2048 + grow) * 16 + hh] = m_[r];
        l_part[((size_t)j4 * 2048 + grow) * 16 + hh] = l_[r];
      }
      #pragma unroll
      for (int nt = 0; nt < 4; ++nt)
        o_part[((size_t)j4 * 2048 + grow) * 1024 + hh * 64 + nt * 16 + l16] = accO[nt][r];
    }
  }
}

// ---------------- merge 4 KV-partials -> y (bf16) ---------------------------
__global__ __launch_bounds__(256) void attnmerge_k(const float* __restrict__ o_part,
    const float* __restrict__ m_part, const float* __restrict__ l_part,
    const float* __restrict__ sbr, const float* __restrict__ pl2s,
    __bf16* __restrict__ yo) {
  int idx = blockIdx.x * 256 + threadIdx.x;      // 524288 threads
  int s = idx >> 8, rem = idx & 255;
  int h = rem >> 4, dg = (rem & 15) * 4;
  float m[4], l[4];
  #pragma unroll
  for (int j = 0; j < 4; ++j) {
    m[j] = m_part[((size_t)j * 2048 + s) * 16 + h];
    l[j] = l_part[((size_t)j * 2048 + s) * 16 + h];
  }
  float M = fmaxf(fmaxf(m[0], m[1]), fmaxf(m[2], m[3]));
  float den = 0.f;
  float4 acc = {0.f, 0.f, 0.f, 0.f};
  #pragma unroll
  for (int j = 0; j < 4; ++j) {
    float e = __expf(m[j] - M);
    den += l[j] * e;
    float4 o = *(const float4*)(o_part + ((size_t)j * 2048 + s) * 1024 + h * 64 + dg);
    acc.x += e * o.x; acc.y += e * o.y; acc.z += e * o.z; acc.w += e * o.w;
  }
  float sc = pl2s[0] / den;
  float add = sbr[s * 16 + h];
  __bf16* yp = yo + (size_t)s * 1024 + h * 64 + dg;
  yp[0] = (__bf16)(sc * acc.x + add);
  yp[1] = (__bf16)(sc * acc.y + add);
  yp[2] = (__bf16)(sc * acc.z + add);
  yp[3] = (__bf16)(sc * acc.w + add);
}

extern "C" void kernel_launch(void* const* d_in, const int* in_sizes, int n_in,
                              void* d_out, int out_size, void* d_ws, size_t ws_size,
                              hipStream_t stream) {
  (void)in_sizes; (void)n_in; (void)out_size; (void)ws_size;
  const float* hs   = (const float*)d_in[0];
  const float* Wq   = (const float*)d_in[1];
  const float* Wk   = (const float*)d_in[2];
  const float* Wv   = (const float*)d_in[3];
  const float* Wqb  = (const float*)d_in[4];
  const float* Wkb  = (const float*)d_in[5];
  const float* Wo   = (const float*)d_in[6];
  const float* bo   = (const float*)d_in[7];
  const float* W1   = (const float*)d_in[8];
  const float* b1   = (const float*)d_in[9];
  const float* W2   = (const float*)d_in[10];
  const float* b2   = (const float*)d_in[11];
  const float* plam = (const float*)d_in[12];
  const float* pl2s = (const float*)d_in[13];
  float* out = (float*)d_out;
  char* ws = (char*)d_ws;

  size_t off = 0;
  auto alloc = [&](size_t bytes) { char* p = ws + off; off += (bytes + 255) & ~(size_t)255; return p; };
  __bf16* Wt5  = (__bf16*)alloc((size_t)5 * 1024 * 1024 * 2);
  __bf16* Wot  = (__bf16*)alloc((size_t)1024 * 1024 * 2);
  __bf16* W1t  = (__bf16*)alloc((size_t)8192 * 1024 * 2);
  __bf16* W2t  = (__bf16*)alloc((size_t)1024 * 4096 * 2);
  __bf16* xbf  = (__bf16*)alloc((size_t)2048 * 1024 * 2);
  // 64 MB region, sequential reuse:
  //   proj(40) [prep] -> o_part(32, attn partials) -> wo_part(32) / f2_part(32)
  //   qbf32(8) [sbrow] -> m_part/l_part (1) -> overwritten by f2_part
  float*  proj  = (float*)alloc((size_t)2048 * 5120 * 4);
  float*  qbf32 = (float*)alloc((size_t)2048 * 1024 * 4);
  float*  kbf32 = (float*)alloc((size_t)2048 * 1024 * 4);
  __bf16* qbf   = (__bf16*)alloc((size_t)2048 * 1024 * 2);
  __bf16* kbf   = (__bf16*)alloc((size_t)2048 * 1024 * 2);
  float*  o_part  = proj;                                   // 4 x 8 MB
  float*  m_part  = qbf32;                                  // 512 KB
  float*  l_part  = qbf32 + (size_t)4 * 2048 * 16;          // 512 KB
  float*  wo_part = proj;                                   // 4 x 8 MB (after merge)
  float*  f2_part = (float*)((char*)proj + (size_t)32 * 1024 * 1024);  // 4 x 8 MB
  __bf16* vtbf  = (__bf16*)alloc((size_t)1024 * 2048 * 2);
  __bf16* ybf   = (__bf16*)alloc((size_t)2048 * 1024 * 2);
  float*  sbrow = (float*)alloc((size_t)2048 * 16 * 4);
  float*  tsum  = (float*)alloc((size_t)64 * 16 * 64 * 4);
  __bf16* ffin  = (__bf16*)alloc((size_t)2048 * 4096 * 2);

  tconv_k<<<dim3(32, 32), 256, 0, stream>>>(Wq,  Wt5,               1024, 1024);
  tconv_k<<<dim3(32, 32), 256, 0, stream>>>(Wk,  Wt5 + 1048576,     1024, 1024);
  tconv_k<<<dim3(32, 32), 256, 0, stream>>>(Wv,  Wt5 + 2 * 1048576, 1024, 1024);
  tconv_k<<<dim3(32, 32), 256, 0, stream>>>(Wqb, Wt5 + 3 * 1048576, 1024, 1024);
  tconv_k<<<dim3(32, 32), 256, 0, stream>>>(Wkb, Wt5 + 4 * 1048576, 1024, 1024);
  tconv_k<<<dim3(32, 32), 256, 0, stream>>>(Wo,  Wot,               1024, 1024);
  tconv_k<<<dim3(256, 32), 256, 0, stream>>>(W1, W1t,               8192, 1024);
  tconv_k<<<dim3(32, 128), 256, 0, stream>>>(W2, W2t,               1024, 4096);

  rmsnorm_k<<<2048, 256, 0, stream>>>(hs, xbf);
  gemm_bt_k<<<dim3(40, 16), 256, 0, stream>>>(xbf, Wt5, proj, 5120, 1024);
  qkprep_k<<<8192, 256, 0, stream>>>(proj, qbf, kbf, qbf32, kbf32);
  tconv_k<<<dim3(32, 64), 256, 0, stream>>>(proj + 2048, vtbf, 5120, 2048);
  kbsum_k<<<dim3(64, 16), 64, 0, stream>>>(kbf32, tsum);
  sbrow2_k<<<dim3(64, 16), 64, 0, stream>>>(qbf32, kbf32, tsum, sbrow);
  // flash attention partials (1024 blocks) + merge
  attn_k<<<dim3(16, 4, 16), 256, 0, stream>>>(qbf, kbf, vtbf, o_part, m_part, l_part);
  attnmerge_k<<<2048, 256, 0, stream>>>(o_part, m_part, l_part, sbrow, pl2s, ybf);
  // Wo partials: y @ Wo, split-K x4
  gemm_partk_k<<<dim3(8, 16, 4), 256, 0, stream>>>(ybf, Wot, wo_part, 1024, 1024);
  // fused FFN1 + bias + SwiGLU -> ffin (bf16)
  ffn1silu_k<<<dim3(64, 16), 256, 0, stream>>>(xbf, W1t, b1, ffin);
  // FFN2 partials: ffin @ W2, split-K x4
  gemm_partk_k<<<dim3(8, 16, 4), 256, 0, stream>>>(ffin, W2t, f2_part, 1024, 4096);
  // out = Σ f2_part + b2 + Σ wo_part + bo + lam*h
  combine_k<<<2048, 256, 0, stream>>>(f2_part, wo_part, b2, bo, hs, plam, out);
}

// Round 7
// 408.349 us; speedup vs baseline: 1.2496x; 1.0049x over previous
//
#include <hip/hip_runtime.h>
#include <hip/hip_bf16.h>
#include <math.h>

typedef __bf16 bf16x8 __attribute__((ext_vector_type(8)));
typedef float  f32x4  __attribute__((ext_vector_type(4)));

#define GLD16(g, l) __builtin_amdgcn_global_load_lds(                      \
    (const __attribute__((address_space(1))) void*)(g),                    \
    (__attribute__((address_space(3))) void*)(l), 16, 0, 0)

// BK=32 LDS tiles (64 B rows): global k-group g of row r is stored at slot
// g ^ ((r>>1)&3)  -> all ds_read_b128 fragment reads become 2-way (free).
// Swizzle is applied to the GLOBAL source address of global_load_lds (its
// LDS destination is fixed wave-uniform + lane*16).

// ---------------- transpose + f32 -> bf16 convert (out[c][r] = in[r][c]) ----
__global__ __launch_bounds__(256) void tconv_k(const float* __restrict__ in,
                                               __bf16* __restrict__ out,
                                               int ldin, int ldout) {
  __shared__ float t[32][33];
  int c0 = blockIdx.x * 32, r0 = blockIdx.y * 32;
  int tx = threadIdx.x & 31, ty = threadIdx.x >> 5;
  #pragma unroll
  for (int i = ty; i < 32; i += 8)
    t[i][tx] = in[(size_t)(r0 + i) * ldin + c0 + tx];
  __syncthreads();
  #pragma unroll
  for (int i = ty; i < 32; i += 8)
    out[(size_t)(c0 + i) * ldout + r0 + tx] = (__bf16)t[tx][i];
}

// ---------------- RMSNorm ---------------------------------------------------
__global__ __launch_bounds__(256) void rmsnorm_k(const float* __restrict__ hs,
                                                 __bf16* __restrict__ x) {
  int row = blockIdx.x, tid = threadIdx.x;
  const float4 v = ((const float4*)(hs + (size_t)row * 1024))[tid];
  float ss = v.x * v.x + v.y * v.y + v.z * v.z + v.w * v.w;
  #pragma unroll
  for (int o = 32; o > 0; o >>= 1) ss += __shfl_xor(ss, o);
  __shared__ float ps[4];
  if ((tid & 63) == 0) ps[tid >> 6] = ss;
  __syncthreads();
  float tot = ps[0] + ps[1] + ps[2] + ps[3];
  float r = rsqrtf(tot * (1.0f / 1024.0f) + 1.1920929e-7f);
  __bf16* xr = x + (size_t)row * 1024 + tid * 4;
  xr[0] = (__bf16)(v.x * r); xr[1] = (__bf16)(v.y * r);
  xr[2] = (__bf16)(v.z * r); xr[3] = (__bf16)(v.w * r);
}

// ---------------- GEMM 128x128 dbuf, swizzled LDS (plain store) -------------
__global__ __launch_bounds__(256) void gemm_bt_k(
    const __bf16* __restrict__ A, const __bf16* __restrict__ Bt,
    float* __restrict__ C, int N, int K) {
  __shared__ __bf16 sA[2][128 * 32];
  __shared__ __bf16 sB[2][128 * 32];
  const int tid = threadIdx.x;
  const int lane = tid & 63;
  const int quad = lane >> 4, l16 = lane & 15;
  const int wave = tid >> 6;
  const int waveM = wave >> 1, waveN = wave & 1;
  const int m0 = blockIdx.y * 128, n0 = blockIdx.x * 128;
  const int nk = K >> 5;
  const int rowS = tid >> 2;
  const int kg = ((tid & 3) ^ ((rowS >> 1) & 3)) * 8;   // swizzled source group
  const __bf16* gA0 = A + (size_t)(m0 + rowS) * K + kg;
  const __bf16* gA1 = gA0 + (size_t)64 * K;
  const __bf16* gB0 = Bt + (size_t)(n0 + rowS) * K + kg;
  const __bf16* gB1 = gB0 + (size_t)64 * K;
  const int lo0 = tid * 8, lo1 = 2048 + tid * 8;

  GLD16(gA0, sA[0] + lo0);
  GLD16(gA1, sA[0] + lo1);
  GLD16(gB0, sB[0] + lo0);
  GLD16(gB1, sB[0] + lo1);

  f32x4 acc[4][4] = {};
  for (int i = 0; i < nk; ++i) {
    __syncthreads();
    if (i + 1 < nk) {
      const int k = (i + 1) * 32;
      __bf16* dA = sA[(i + 1) & 1];
      __bf16* dB = sB[(i + 1) & 1];
      GLD16(gA0 + k, dA + lo0);
      GLD16(gA1 + k, dA + lo1);
      GLD16(gB0 + k, dB + lo0);
      GLD16(gB1 + k, dB + lo1);
    }
    const __bf16* cA = sA[i & 1];
    const __bf16* cB = sB[i & 1];
    bf16x8 af[4], bfv[4];
    #pragma unroll
    for (int mt = 0; mt < 4; ++mt) {
      int r = waveM * 64 + mt * 16 + l16;
      af[mt] = *(const bf16x8*)(cA + r * 32 + ((quad ^ ((r >> 1) & 3)) * 8));
    }
    #pragma unroll
    for (int nt = 0; nt < 4; ++nt) {
      int r = waveN * 64 + nt * 16 + l16;
      bfv[nt] = *(const bf16x8*)(cB + r * 32 + ((quad ^ ((r >> 1) & 3)) * 8));
    }
    #pragma unroll
    for (int mt = 0; mt < 4; ++mt)
      #pragma unroll
      for (int nt = 0; nt < 4; ++nt)
        acc[mt][nt] = __builtin_amdgcn_mfma_f32_16x16x32_bf16(af[mt], bfv[nt], acc[mt][nt], 0, 0, 0);
  }
  #pragma unroll
  for (int mt = 0; mt < 4; ++mt) {
    int row = m0 + waveM * 64 + mt * 16 + quad * 4;
    #pragma unroll
    for (int nt = 0; nt < 4; ++nt) {
      int col = n0 + waveN * 64 + nt * 16 + l16;
      #pragma unroll
      for (int r = 0; r < 4; ++r)
        C[(size_t)(row + r) * N + col] = acc[mt][nt][r];
    }
  }
}

// ---------------- GEMM 128x128 dbuf, swizzled, split-K partial buffers ------
__global__ __launch_bounds__(256) void gemm_partk_k(
    const __bf16* __restrict__ A, const __bf16* __restrict__ Bt,
    float* __restrict__ P, int N, int K) {
  __shared__ __bf16 sA[2][128 * 32];
  __shared__ __bf16 sB[2][128 * 32];
  const int tid = threadIdx.x;
  const int lane = tid & 63;
  const int quad = lane >> 4, l16 = lane & 15;
  const int wave = tid >> 6;
  const int waveM = wave >> 1, waveN = wave & 1;
  const int m0 = blockIdx.y * 128, n0 = blockIdx.x * 128;
  const int kz = blockIdx.z, nz = gridDim.z;
  const int kper = K / nz, kbeg = kz * kper;
  const int nk = kper >> 5;
  const size_t MN = (size_t)gridDim.y * 128 * N;
  float* C = P + (size_t)kz * MN;
  const int rowS = tid >> 2;
  const int kg = ((tid & 3) ^ ((rowS >> 1) & 3)) * 8;
  const __bf16* gA0 = A + (size_t)(m0 + rowS) * K + kbeg + kg;
  const __bf16* gA1 = gA0 + (size_t)64 * K;
  const __bf16* gB0 = Bt + (size_t)(n0 + rowS) * K + kbeg + kg;
  const __bf16* gB1 = gB0 + (size_t)64 * K;
  const int lo0 = tid * 8, lo1 = 2048 + tid * 8;

  GLD16(gA0, sA[0] + lo0);
  GLD16(gA1, sA[0] + lo1);
  GLD16(gB0, sB[0] + lo0);
  GLD16(gB1, sB[0] + lo1);

  f32x4 acc[4][4] = {};
  for (int i = 0; i < nk; ++i) {
    __syncthreads();
    if (i + 1 < nk) {
      const int k = (i + 1) * 32;
      __bf16* dA = sA[(i + 1) & 1];
      __bf16* dB = sB[(i + 1) & 1];
      GLD16(gA0 + k, dA + lo0);
      GLD16(gA1 + k, dA + lo1);
      GLD16(gB0 + k, dB + lo0);
      GLD16(gB1 + k, dB + lo1);
    }
    const __bf16* cA = sA[i & 1];
    const __bf16* cB = sB[i & 1];
    bf16x8 af[4], bfv[4];
    #pragma unroll
    for (int mt = 0; mt < 4; ++mt) {
      int r = waveM * 64 + mt * 16 + l16;
      af[mt] = *(const bf16x8*)(cA + r * 32 + ((quad ^ ((r >> 1) & 3)) * 8));
    }
    #pragma unroll
    for (int nt = 0; nt < 4; ++nt) {
      int r = waveN * 64 + nt * 16 + l16;
      bfv[nt] = *(const bf16x8*)(cB + r * 32 + ((quad ^ ((r >> 1) & 3)) * 8));
    }
    #pragma unroll
    for (int mt = 0; mt < 4; ++mt)
      #pragma unroll
      for (int nt = 0; nt < 4; ++nt)
        acc[mt][nt] = __builtin_amdgcn_mfma_f32_16x16x32_bf16(af[mt], bfv[nt], acc[mt][nt], 0, 0, 0);
  }
  #pragma unroll
  for (int mt = 0; mt < 4; ++mt) {
    int row = m0 + waveM * 64 + mt * 16 + quad * 4;
    #pragma unroll
    for (int nt = 0; nt < 4; ++nt) {
      int col = n0 + waveN * 64 + nt * 16 + l16;
      #pragma unroll
      for (int r = 0; r < 4; ++r)
        C[(size_t)(row + r) * N + col] = acc[mt][nt][r];
    }
  }
}

// ---------------- fused FFN1 + bias + SwiGLU (64x32 wave tiles, swizzled) ---
__global__ __launch_bounds__(256) void ffn1silu_k(
    const __bf16* __restrict__ A, const __bf16* __restrict__ W1t,
    const float* __restrict__ b1, __bf16* __restrict__ ffin) {
  __shared__ __bf16 sA[2][128 * 32];
  __shared__ __bf16 sBx[2][64 * 32];
  __shared__ __bf16 sBg[2][64 * 32];
  const int tid = threadIdx.x, lane = tid & 63, w = tid >> 6;
  const int quad = lane >> 4, l16 = lane & 15;
  const int wm = w >> 1, wn = w & 1;
  const int m0 = blockIdx.y * 128, n0 = blockIdx.x * 64;
  const int K = 1024, nk = 32;
  const int rowS = tid >> 2;
  const int kg = ((tid & 3) ^ ((rowS >> 1) & 3)) * 8;
  const __bf16* gA0 = A + (size_t)(m0 + rowS) * K + kg;
  const __bf16* gA1 = gA0 + (size_t)64 * K;
  const __bf16* gBx = W1t + (size_t)(n0 + rowS) * K + kg;
  const __bf16* gBg = W1t + (size_t)(4096 + n0 + rowS) * K + kg;
  const int lo = tid * 8;

  GLD16(gA0, sA[0] + lo);
  GLD16(gA1, sA[0] + 2048 + lo);
  GLD16(gBx, sBx[0] + lo);
  GLD16(gBg, sBg[0] + lo);

  f32x4 ax[4][2] = {}, ag[4][2] = {};
  for (int i = 0; i < nk; ++i) {
    __syncthreads();
    if (i + 1 < nk) {
      const int k = (i + 1) * 32, b = (i + 1) & 1;
      GLD16(gA0 + k, sA[b] + lo);
      GLD16(gA1 + k, sA[b] + 2048 + lo);
      GLD16(gBx + k, sBx[b] + lo);
      GLD16(gBg + k, sBg[b] + lo);
    }
    const __bf16* cA = sA[i & 1];
    const __bf16* cx = sBx[i & 1];
    const __bf16* cg = sBg[i & 1];
    bf16x8 af[4], bx[2], bg[2];
    #pragma unroll
    for (int mt = 0; mt < 4; ++mt) {
      int r = wm * 64 + mt * 16 + l16;
      af[mt] = *(const bf16x8*)(cA + r * 32 + ((quad ^ ((r >> 1) & 3)) * 8));
    }
    #pragma unroll
    for (int nt = 0; nt < 2; ++nt) {
      int r = wn * 32 + nt * 16 + l16;
      int sl = (quad ^ ((r >> 1) & 3)) * 8;
      bx[nt] = *(const bf16x8*)(cx + r * 32 + sl);
      bg[nt] = *(const bf16x8*)(cg + r * 32 + sl);
    }
    #pragma unroll
    for (int mt = 0; mt < 4; ++mt)
      #pragma unroll
      for (int nt = 0; nt < 2; ++nt) {
        ax[mt][nt] = __builtin_amdgcn_mfma_f32_16x16x32_bf16(af[mt], bx[nt], ax[mt][nt], 0, 0, 0);
        ag[mt][nt] = __builtin_amdgcn_mfma_f32_16x16x32_bf16(af[mt], bg[nt], ag[mt][nt], 0, 0, 0);
      }
  }
  #pragma unroll
  for (int mt = 0; mt < 4; ++mt) {
    int row = m0 + wm * 64 + mt * 16 + quad * 4;
    #pragma unroll
    for (int nt = 0; nt < 2; ++nt) {
      int col = n0 + wn * 32 + nt * 16 + l16;
      float bxv = b1[col], bgv = b1[col + 4096];
      #pragma unroll
      for (int r = 0; r < 4; ++r) {
        float xp = ax[mt][nt][r] + bxv;
        float g  = ag[mt][nt][r] + bgv;
        float val = xp * g / (1.f + __expf(-g));
        ffin[(size_t)(row + r) * 4096 + col] = (__bf16)val;
      }
    }
  }
}

// ---------------- combine: out = Σ4 ffn2_p + b2 + Σ4 wo_p + bo + lam*h -----
__global__ __launch_bounds__(256) void combine_k(
    const float* __restrict__ f2p, const float* __restrict__ wop,
    const float* __restrict__ b2, const float* __restrict__ bo,
    const float* __restrict__ hs, const float* __restrict__ plam,
    float* __restrict__ out) {
  const size_t MN = (size_t)2048 * 1024;
  size_t i = ((size_t)blockIdx.x * 256 + threadIdx.x) * 4;
  int col = (int)(i & 1023);
  float4 a0 = *(const float4*)(f2p + i);
  float4 a1 = *(const float4*)(f2p + MN + i);
  float4 a2 = *(const float4*)(f2p + 2 * MN + i);
  float4 a3 = *(const float4*)(f2p + 3 * MN + i);
  float4 w0 = *(const float4*)(wop + i);
  float4 w1 = *(const float4*)(wop + MN + i);
  float4 w2 = *(const float4*)(wop + 2 * MN + i);
  float4 w3 = *(const float4*)(wop + 3 * MN + i);
  float4 h  = *(const float4*)(hs + i);
  float4 v2 = *(const float4*)(b2 + col);
  float4 vo = *(const float4*)(bo + col);
  float lam = plam[0];
  float4 o;
  o.x = (a0.x + a1.x) + (a2.x + a3.x) + v2.x + (w0.x + w1.x) + (w2.x + w3.x) + vo.x + lam * h.x;
  o.y = (a0.y + a1.y) + (a2.y + a3.y) + v2.y + (w0.y + w1.y) + (w2.y + w3.y) + vo.y + lam * h.y;
  o.z = (a0.z + a1.z) + (a2.z + a3.z) + v2.z + (w0.z + w1.z) + (w2.z + w3.z) + vo.z + lam * h.z;
  o.w = (a0.w + a1.w) + (a2.w + a3.w) + v2.w + (w0.w + w1.w) + (w2.w + w3.w) + vo.w + lam * h.w;
  *(float4*)(out + i) = o;
}

// ---------------- l2norm + RoPE for q,k,qb,kb -------------------------------
__global__ __launch_bounds__(256) void qkprep_k(const float* __restrict__ proj,
    __bf16* __restrict__ qo, __bf16* __restrict__ ko,
    float* __restrict__ qbo, float* __restrict__ kbo) {
  int gw = blockIdx.x * 4 + (threadIdx.x >> 6);
  int lane = threadIdx.x & 63;
  int s = gw >> 4, h = gw & 15;
  int j = lane & 31;
  float inv = powf(1000.0f, -(float)j * (1.0f / 32.0f));
  float ang = (float)s * inv;
  float cb = (float)(__bf16)cosf(ang);
  float sb = (float)(__bf16)sinf(ang);
  size_t ibase = (size_t)s * 5120 + h * 64 + lane;
  size_t obase = (size_t)s * 1024 + h * 64 + lane;
  bool lo = lane < 32;

  auto proc = [&](const float* src) -> float {
    float xv = src[ibase];
    float ss = xv * xv;
    #pragma unroll
    for (int o = 32; o > 0; o >>= 1) ss += __shfl_xor(ss, o);
    float y = xv / fmaxf(sqrtf(ss), 1e-12f);
    float yp = __shfl_xor(y, 32);
    return lo ? (y * cb + yp * sb) : (y * cb - yp * sb);
  };
  qo[obase]  = (__bf16)proc(proj + 0);
  ko[obase]  = (__bf16)proc(proj + 1024);
  qbo[obase] = proc(proj + 3072);
  kbo[obase] = proc(proj + 4096);
}

// ---------------- sb row-sum via two-level cumsum ---------------------------
__global__ __launch_bounds__(64) void kbsum_k(const float* __restrict__ kb,
                                              float* __restrict__ tsum) {
  int t = blockIdx.x, h = blockIdx.y, d = threadIdx.x;
  size_t base = (size_t)h * 64 + d;
  float s = 0.f;
  #pragma unroll 4
  for (int r = 0; r < 32; ++r)
    s += kb[(size_t)(t * 32 + r) * 1024 + base];
  tsum[(t * 16 + h) * 64 + d] = s;
}

__global__ __launch_bounds__(64) void sbrow2_k(const float* __restrict__ qb,
                                               const float* __restrict__ kb,
                                               const float* __restrict__ tsum,
                                               float* __restrict__ sb) {
  int t = blockIdx.x, h = blockIdx.y, d = threadIdx.x;
  size_t base = (size_t)h * 64 + d;
  float run = 0.f;
  for (int tp = 0; tp < t; ++tp) run += tsum[(tp * 16 + h) * 64 + d];
  for (int s0 = 0; s0 < 32; s0 += 4) {
    float p[4];
    #pragma unroll
    for (int u = 0; u < 4; ++u) {
      size_t off = (size_t)(t * 32 + s0 + u) * 1024 + base;
      run += kb[off];
      p[u] = qb[off] * run;
    }
    #pragma unroll
    for (int o = 32; o > 0; o >>= 1) {
      #pragma unroll
      for (int u = 0; u < 4; ++u) p[u] += __shfl_xor(p[u], o);
    }
    if (d == 0) {
      #pragma unroll
      for (int u = 0; u < 4; ++u) sb[(t * 32 + s0 + u) * 16 + h] = 0.125f * p[u];
    }
  }
}

// ---------------- flash attention: split-KV x4, swizzled LDS ----------------
__global__ __launch_bounds__(256) void attn_k(const __bf16* __restrict__ qg,
    const __bf16* __restrict__ kg, const __bf16* __restrict__ vtg,
    float* __restrict__ o_part, float* __restrict__ m_part,
    float* __restrict__ l_part) {
  __shared__ __bf16 sK[64 * 64];
  __shared__ __bf16 sVt[64 * 64];
  __shared__ __bf16 sP[4][16 * 64];
  const int pair = blockIdx.x, j4 = blockIdx.y, hh = blockIdx.z;
  const int tid = threadIdx.x, lane = tid & 63, w = tid >> 6;
  const int quad = lane >> 4, l16 = lane & 15;
  const int srow = tid >> 3;
  const int sg = (tid & 7) ^ (srow & 7);
  __bf16* ldsK = sK + tid * 8;
  __bf16* ldsV = sVt + tid * 8;
  __bf16* sPw = sP[w];

  for (int phase = 0; phase < 2; ++phase) {
    const int qt = phase ? 31 - pair : pair;
    const int q0 = qt * 64;
    const int n = qt + 1;
    const int kb = (j4 * n) >> 2, ke = ((j4 + 1) * n) >> 2;
    bf16x8 qf[2];
    #pragma unroll
    for (int kk = 0; kk < 2; ++kk)
      qf[kk] = *(const bf16x8*)(qg + (size_t)(q0 + w * 16 + l16) * 1024 + hh * 64 + kk * 32 + quad * 8);
    f32x4 accO[4] = {};
    float m_[4], l_[4];
    #pragma unroll
    for (int r = 0; r < 4; ++r) { m_[r] = -INFINITY; l_[r] = 0.f; }

    for (int kt = kb; kt < ke; ++kt) {
      const __bf16* gK = kg + (size_t)(kt * 64 + srow) * 1024 + hh * 64 + sg * 8;
      const __bf16* gV = vtg + (size_t)(hh * 64 + srow) * 2048 + kt * 64 + sg * 8;
      GLD16(gK, ldsK);
      GLD16(gK + (size_t)32 * 1024, ldsK + 2048);
      GLD16(gV, ldsV);
      GLD16(gV + (size_t)32 * 2048, ldsV + 2048);
      __syncthreads();

      f32x4 s4[4];
      #pragma unroll
      for (int nt = 0; nt < 4; ++nt) {
        int r = nt * 16 + l16;
        bf16x8 b0 = *(const bf16x8*)(sK + r * 64 + ((quad ^ (r & 7)) * 8));
        bf16x8 b1 = *(const bf16x8*)(sK + r * 64 + (((4 + quad) ^ (r & 7)) * 8));
        f32x4 sa = {0.f, 0.f, 0.f, 0.f};
        sa = __builtin_amdgcn_mfma_f32_16x16x32_bf16(qf[0], b0, sa, 0, 0, 0);
        sa = __builtin_amdgcn_mfma_f32_16x16x32_bf16(qf[1], b1, sa, 0, 0, 0);
        s4[nt] = sa;
      }
      if (kt == qt) {
        #pragma unroll
        for (int nt = 0; nt < 4; ++nt)
          #pragma unroll
          for (int r = 0; r < 4; ++r)
            if (nt * 16 + l16 > w * 16 + quad * 4 + r) s4[nt][r] = -INFINITY;
      }
      float mx[4], al[4], rs[4];
      #pragma unroll
      for (int r = 0; r < 4; ++r)
        mx[r] = fmaxf(fmaxf(s4[0][r], s4[1][r]), fmaxf(s4[2][r], s4[3][r]));
      #pragma unroll
      for (int o = 1; o < 16; o <<= 1)
        #pragma unroll
        for (int r = 0; r < 4; ++r) mx[r] = fmaxf(mx[r], __shfl_xor(mx[r], o));
      #pragma unroll
      for (int r = 0; r < 4; ++r) {
        float mn = fmaxf(m_[r], mx[r]);
        al[r] = __expf(m_[r] - mn);
        m_[r] = mn;
      }
      float p[4][4];
      #pragma unroll
      for (int nt = 0; nt < 4; ++nt)
        #pragma unroll
        for (int r = 0; r < 4; ++r)
          p[nt][r] = __expf(s4[nt][r] - m_[r]);
      #pragma unroll
      for (int r = 0; r < 4; ++r)
        rs[r] = (p[0][r] + p[1][r]) + (p[2][r] + p[3][r]);
      #pragma unroll
      for (int o = 1; o < 16; o <<= 1)
        #pragma unroll
        for (int r = 0; r < 4; ++r) rs[r] += __shfl_xor(rs[r], o);
      #pragma unroll
      for (int r = 0; r < 4; ++r) l_[r] = l_[r] * al[r] + rs[r];
      #pragma unroll
      for (int nt = 0; nt < 4; ++nt)
        #pragma unroll
        for (int r = 0; r < 4; ++r) accO[nt][r] *= al[r];
      #pragma unroll
      for (int nt = 0; nt < 4; ++nt)
        #pragma unroll
        for (int r = 0; r < 4; ++r) {
          int row = quad * 4 + r, col = nt * 16 + l16;
          sPw[row * 64 + (col ^ ((row & 7) << 3))] = (__bf16)p[nt][r];
        }
      #pragma unroll
      for (int kk = 0; kk < 2; ++kk) {
        bf16x8 a = *(const bf16x8*)(sPw + l16 * 64 + (((kk * 4 + quad) ^ (l16 & 7)) * 8));
        #pragma unroll
        for (int nt = 0; nt < 4; ++nt) {
          int vr = nt * 16 + l16;
          bf16x8 bv = *(const bf16x8*)(sVt + vr * 64 + (((kk * 4 + quad) ^ (vr & 7)) * 8));
          accO[nt] = __builtin_amdgcn_mfma_f32_16x16x32_bf16(a, bv, accO[nt], 0, 0, 0);
        }
      }
      __syncthreads();
    }
    #pragma unroll
    for (int r = 0; r < 4; ++r) {
      int grow = q0 + w * 16 + quad * 4 + r;
      if (l16 == 0) {
        m_part[((size_t)j4 * 2048 + grow) * 16 + hh] = m_[r];
        l_part[((size_t)j4 * 2048 + grow) * 16 + hh] = l_[r];
      }
      #pragma unroll
      for (int nt = 0; nt < 4; ++nt)
        o_part[((size_t)j4 * 2048 + grow) * 1024 + hh * 64 + nt * 16 + l16] = accO[nt][r];
    }
  }
}

// ---------------- merge 4 KV-partials -> y (bf16) ---------------------------
__global__ __launch_bounds__(256) void attnmerge_k(const float* __restrict__ o_part,
    const float* __restrict__ m_part, const float* __restrict__ l_part,
    const float* __restrict__ sbr, const float* __restrict__ pl2s,
    __bf16* __restrict__ yo) {
  int idx = blockIdx.x * 256 + threadIdx.x;
  int s = idx >> 8, rem = idx & 255;
  int h = rem >> 4, dg = (rem & 15) * 4;
  float m[4], l[4];
  #pragma unroll
  for (int j = 0; j < 4; ++j) {
    m[j] = m_part[((size_t)j * 2048 + s) * 16 + h];
    l[j] = l_part[((size_t)j * 2048 + s) * 16 + h];
  }
  float M = fmaxf(fmaxf(m[0], m[1]), fmaxf(m[2], m[3]));
  float den = 0.f;
  float4 acc = {0.f, 0.f, 0.f, 0.f};
  #pragma unroll
  for (int j = 0; j < 4; ++j) {
    float e = __expf(m[j] - M);
    den += l[j] * e;
    float4 o = *(const float4*)(o_part + ((size_t)j * 2048 + s) * 1024 + h * 64 + dg);
    acc.x += e * o.x; acc.y += e * o.y; acc.z += e * o.z; acc.w += e * o.w;
  }
  float sc = pl2s[0] / den;
  float add = sbr[s * 16 + h];
  __bf16* yp = yo + (size_t)s * 1024 + h * 64 + dg;
  yp[0] = (__bf16)(sc * acc.x + add);
  yp[1] = (__bf16)(sc * acc.y + add);
  yp[2] = (__bf16)(sc * acc.z + add);
  yp[3] = (__bf16)(sc * acc.w + add);
}

extern "C" void kernel_launch(void* const* d_in, const int* in_sizes, int n_in,
                              void* d_out, int out_size, void* d_ws, size_t ws_size,
                              hipStream_t stream) {
  (void)in_sizes; (void)n_in; (void)out_size; (void)ws_size;
  const float* hs   = (const float*)d_in[0];
  const float* Wq   = (const float*)d_in[1];
  const float* Wk   = (const float*)d_in[2];
  const float* Wv   = (const float*)d_in[3];
  const float* Wqb  = (const float*)d_in[4];
  const float* Wkb  = (const float*)d_in[5];
  const float* Wo   = (const float*)d_in[6];
  const float* bo   = (const float*)d_in[7];
  const float* W1   = (const float*)d_in[8];
  const float* b1   = (const float*)d_in[9];
  const float* W2   = (const float*)d_in[10];
  const float* b2   = (const float*)d_in[11];
  const float* plam = (const float*)d_in[12];
  const float* pl2s = (const float*)d_in[13];
  float* out = (float*)d_out;
  char* ws = (char*)d_ws;

  size_t off = 0;
  auto alloc = [&](size_t bytes) { char* p = ws + off; off += (bytes + 255) & ~(size_t)255; return p; };
  __bf16* Wt5  = (__bf16*)alloc((size_t)5 * 1024 * 1024 * 2);
  __bf16* Wot  = (__bf16*)alloc((size_t)1024 * 1024 * 2);
  __bf16* W1t  = (__bf16*)alloc((size_t)8192 * 1024 * 2);
  __bf16* W2t  = (__bf16*)alloc((size_t)1024 * 4096 * 2);
  __bf16* xbf  = (__bf16*)alloc((size_t)2048 * 1024 * 2);
  float*  proj  = (float*)alloc((size_t)2048 * 5120 * 4);
  float*  qbf32 = (float*)alloc((size_t)2048 * 1024 * 4);
  float*  kbf32 = (float*)alloc((size_t)2048 * 1024 * 4);
  __bf16* qbf   = (__bf16*)alloc((size_t)2048 * 1024 * 2);
  __bf16* kbf   = (__bf16*)alloc((size_t)2048 * 1024 * 2);
  float*  o_part  = proj;                                   // 4 x 8 MB
  float*  m_part  = qbf32;                                  // 512 KB
  float*  l_part  = qbf32 + (size_t)4 * 2048 * 16;          // 512 KB
  float*  wo_part = proj;                                   // 4 x 8 MB (after merge)
  float*  f2_part = (float*)((char*)proj + (size_t)32 * 1024 * 1024);  // 4 x 8 MB
  __bf16* vtbf  = (__bf16*)alloc((size_t)1024 * 2048 * 2);
  __bf16* ybf   = (__bf16*)alloc((size_t)2048 * 1024 * 2);
  float*  sbrow = (float*)alloc((size_t)2048 * 16 * 4);
  float*  tsum  = (float*)alloc((size_t)64 * 16 * 64 * 4);
  __bf16* ffin  = (__bf16*)alloc((size_t)2048 * 4096 * 2);

  tconv_k<<<dim3(32, 32), 256, 0, stream>>>(Wq,  Wt5,               1024, 1024);
  tconv_k<<<dim3(32, 32), 256, 0, stream>>>(Wk,  Wt5 + 1048576,     1024, 1024);
  tconv_k<<<dim3(32, 32), 256, 0, stream>>>(Wv,  Wt5 + 2 * 1048576, 1024, 1024);
  tconv_k<<<dim3(32, 32), 256, 0, stream>>>(Wqb, Wt5 + 3 * 1048576, 1024, 1024);
  tconv_k<<<dim3(32, 32), 256, 0, stream>>>(Wkb, Wt5 + 4 * 1048576, 1024, 1024);
  tconv_k<<<dim3(32, 32), 256, 0, stream>>>(Wo,  Wot,               1024, 1024);
  tconv_k<<<dim3(256, 32), 256, 0, stream>>>(W1, W1t,               8192, 1024);
  tconv_k<<<dim3(32, 128), 256, 0, stream>>>(W2, W2t,               1024, 4096);

  rmsnorm_k<<<2048, 256, 0, stream>>>(hs, xbf);
  gemm_bt_k<<<dim3(40, 16), 256, 0, stream>>>(xbf, Wt5, proj, 5120, 1024);
  qkprep_k<<<8192, 256, 0, stream>>>(proj, qbf, kbf, qbf32, kbf32);
  tconv_k<<<dim3(32, 64), 256, 0, stream>>>(proj + 2048, vtbf, 5120, 2048);
  kbsum_k<<<dim3(64, 16), 64, 0, stream>>>(kbf32, tsum);
  sbrow2_k<<<dim3(64, 16), 64, 0, stream>>>(qbf32, kbf32, tsum, sbrow);
  attn_k<<<dim3(16, 4, 16), 256, 0, stream>>>(qbf, kbf, vtbf, o_part, m_part, l_part);
  attnmerge_k<<<2048, 256, 0, stream>>>(o_part, m_part, l_part, sbrow, pl2s, ybf);
  gemm_partk_k<<<dim3(8, 16, 4), 256, 0, stream>>>(ybf, Wot, wo_part, 1024, 1024);
  ffn1silu_k<<<dim3(64, 16), 256, 0, stream>>>(xbf, W1t, b1, ffin);
  gemm_partk_k<<<dim3(8, 16, 4), 256, 0, stream>>>(ffin, W2t, f2_part, 1024, 4096);
  combine_k<<<2048, 256, 0, stream>>>(f2_part, wo_part, b2, bo, hs, plam, out);
}

// Round 8
// 376.067 us; speedup vs baseline: 1.3569x; 1.0858x over previous
//
#include <hip/hip_runtime.h>
#include <hip/hip_bf16.h>
#include <math.h>

typedef __bf16 bf16x8 __attribute__((ext_vector_type(8)));
typedef float  f32x4  __attribute__((ext_vector_type(4)));

#define GLD16(g, l) __builtin_amdgcn_global_load_lds(                      \
    (const __attribute__((address_space(1))) void*)(g),                    \
    (__attribute__((address_space(3))) void*)(l), 16, 0, 0)

// BK=32 LDS tiles (64 B rows): global k-group g of row r stored at slot
// g ^ ((r>>1)&3) -> all ds_read_b128 fragment reads are 2-way (free).

// ---------------- generic 32x32 transpose tile body -------------------------
__device__ __forceinline__ void tconv_tile(const float* __restrict__ in,
                                           __bf16* __restrict__ out,
                                           int ldin, int ldout,
                                           int r0, int c0, int tid) {
  __shared__ float t[32][33];
  int tx = tid & 31, ty = tid >> 5;
  #pragma unroll
  for (int i = ty; i < 32; i += 8)
    t[i][tx] = in[(size_t)(r0 + i) * ldin + c0 + tx];
  __syncthreads();
  #pragma unroll
  for (int i = ty; i < 32; i += 8)
    out[(size_t)(c0 + i) * ldout + r0 + tx] = (__bf16)t[tx][i];
}

// plain transpose (used for V^T from proj)
__global__ __launch_bounds__(256) void tconv_k(const float* __restrict__ in,
                                               __bf16* __restrict__ out,
                                               int ldin, int ldout) {
  tconv_tile(in, out, ldin, ldout, blockIdx.y * 32, blockIdx.x * 32, threadIdx.x);
}

// batched: 5 QKV-family weights (1024x1024 each) -> Wt5 (5 blocks of 1024x1024)
__global__ __launch_bounds__(256) void tconv5_k(const float* __restrict__ w0,
    const float* __restrict__ w1, const float* __restrict__ w2,
    const float* __restrict__ w3, const float* __restrict__ w4,
    __bf16* __restrict__ out) {
  const float* src[5] = {w0, w1, w2, w3, w4};
  int z = blockIdx.z;
  tconv_tile(src[z], out + (size_t)z * 1048576, 1024, 1024,
             blockIdx.y * 32, blockIdx.x * 32, threadIdx.x);
}

// batched: Wo (1024x1024) -> WoW2t cols 0..1023 ; W2 (4096x1024) -> cols 1024..
__global__ __launch_bounds__(256) void tconvwow2_k(const float* __restrict__ Wo,
    const float* __restrict__ W2, __bf16* __restrict__ WoW2t) {
  int tid = threadIdx.x;
  if (blockIdx.z == 0) {
    if (blockIdx.y >= 32) return;
    // out[c][r] at stride 5120, offset 0
    __shared__ float t[32][33];
    int r0 = blockIdx.y * 32, c0 = blockIdx.x * 32;
    int tx = tid & 31, ty = tid >> 5;
    #pragma unroll
    for (int i = ty; i < 32; i += 8)
      t[i][tx] = Wo[(size_t)(r0 + i) * 1024 + c0 + tx];
    __syncthreads();
    #pragma unroll
    for (int i = ty; i < 32; i += 8)
      WoW2t[(size_t)(c0 + i) * 5120 + r0 + tx] = (__bf16)t[tx][i];
  } else {
    __shared__ float t[32][33];
    int r0 = blockIdx.y * 32, c0 = blockIdx.x * 32;
    int tx = tid & 31, ty = tid >> 5;
    #pragma unroll
    for (int i = ty; i < 32; i += 8)
      t[i][tx] = W2[(size_t)(r0 + i) * 1024 + c0 + tx];
    __syncthreads();
    #pragma unroll
    for (int i = ty; i < 32; i += 8)
      WoW2t[(size_t)(c0 + i) * 5120 + 1024 + r0 + tx] = (__bf16)t[tx][i];
  }
}

// ---------------- RMSNorm ---------------------------------------------------
__global__ __launch_bounds__(256) void rmsnorm_k(const float* __restrict__ hs,
                                                 __bf16* __restrict__ x) {
  int row = blockIdx.x, tid = threadIdx.x;
  const float4 v = ((const float4*)(hs + (size_t)row * 1024))[tid];
  float ss = v.x * v.x + v.y * v.y + v.z * v.z + v.w * v.w;
  #pragma unroll
  for (int o = 32; o > 0; o >>= 1) ss += __shfl_xor(ss, o);
  __shared__ float ps[4];
  if ((tid & 63) == 0) ps[tid >> 6] = ss;
  __syncthreads();
  float tot = ps[0] + ps[1] + ps[2] + ps[3];
  float r = rsqrtf(tot * (1.0f / 1024.0f) + 1.1920929e-7f);
  __bf16* xr = x + (size_t)row * 1024 + tid * 4;
  xr[0] = (__bf16)(v.x * r); xr[1] = (__bf16)(v.y * r);
  xr[2] = (__bf16)(v.z * r); xr[3] = (__bf16)(v.w * r);
}

// ---------------- GEMM 128x128 dbuf, swizzled LDS (plain store) -------------
__global__ __launch_bounds__(256) void gemm_bt_k(
    const __bf16* __restrict__ A, const __bf16* __restrict__ Bt,
    float* __restrict__ C, int N, int K) {
  __shared__ __bf16 sA[2][128 * 32];
  __shared__ __bf16 sB[2][128 * 32];
  const int tid = threadIdx.x;
  const int lane = tid & 63;
  const int quad = lane >> 4, l16 = lane & 15;
  const int wave = tid >> 6;
  const int waveM = wave >> 1, waveN = wave & 1;
  const int m0 = blockIdx.y * 128, n0 = blockIdx.x * 128;
  const int nk = K >> 5;
  const int rowS = tid >> 2;
  const int kg = ((tid & 3) ^ ((rowS >> 1) & 3)) * 8;
  const __bf16* gA0 = A + (size_t)(m0 + rowS) * K + kg;
  const __bf16* gA1 = gA0 + (size_t)64 * K;
  const __bf16* gB0 = Bt + (size_t)(n0 + rowS) * K + kg;
  const __bf16* gB1 = gB0 + (size_t)64 * K;
  const int lo0 = tid * 8, lo1 = 2048 + tid * 8;

  GLD16(gA0, sA[0] + lo0);
  GLD16(gA1, sA[0] + lo1);
  GLD16(gB0, sB[0] + lo0);
  GLD16(gB1, sB[0] + lo1);

  f32x4 acc[4][4] = {};
  for (int i = 0; i < nk; ++i) {
    __syncthreads();
    if (i + 1 < nk) {
      const int k = (i + 1) * 32;
      __bf16* dA = sA[(i + 1) & 1];
      __bf16* dB = sB[(i + 1) & 1];
      GLD16(gA0 + k, dA + lo0);
      GLD16(gA1 + k, dA + lo1);
      GLD16(gB0 + k, dB + lo0);
      GLD16(gB1 + k, dB + lo1);
    }
    const __bf16* cA = sA[i & 1];
    const __bf16* cB = sB[i & 1];
    bf16x8 af[4], bfv[4];
    #pragma unroll
    for (int mt = 0; mt < 4; ++mt) {
      int r = waveM * 64 + mt * 16 + l16;
      af[mt] = *(const bf16x8*)(cA + r * 32 + ((quad ^ ((r >> 1) & 3)) * 8));
    }
    #pragma unroll
    for (int nt = 0; nt < 4; ++nt) {
      int r = waveN * 64 + nt * 16 + l16;
      bfv[nt] = *(const bf16x8*)(cB + r * 32 + ((quad ^ ((r >> 1) & 3)) * 8));
    }
    #pragma unroll
    for (int mt = 0; mt < 4; ++mt)
      #pragma unroll
      for (int nt = 0; nt < 4; ++nt)
        acc[mt][nt] = __builtin_amdgcn_mfma_f32_16x16x32_bf16(af[mt], bfv[nt], acc[mt][nt], 0, 0, 0);
  }
  #pragma unroll
  for (int mt = 0; mt < 4; ++mt) {
    int row = m0 + waveM * 64 + mt * 16 + quad * 4;
    #pragma unroll
    for (int nt = 0; nt < 4; ++nt) {
      int col = n0 + waveN * 64 + nt * 16 + l16;
      #pragma unroll
      for (int r = 0; r < 4; ++r)
        C[(size_t)(row + r) * N + col] = acc[mt][nt][r];
    }
  }
}

// ---------------- GEMM 128x128 dbuf, swizzled, split-K partial buffers ------
__global__ __launch_bounds__(256) void gemm_partk_k(
    const __bf16* __restrict__ A, const __bf16* __restrict__ Bt,
    float* __restrict__ P, int N, int K) {
  __shared__ __bf16 sA[2][128 * 32];
  __shared__ __bf16 sB[2][128 * 32];
  const int tid = threadIdx.x;
  const int lane = tid & 63;
  const int quad = lane >> 4, l16 = lane & 15;
  const int wave = tid >> 6;
  const int waveM = wave >> 1, waveN = wave & 1;
  const int m0 = blockIdx.y * 128, n0 = blockIdx.x * 128;
  const int kz = blockIdx.z, nz = gridDim.z;
  const int kper = K / nz, kbeg = kz * kper;
  const int nk = kper >> 5;
  const size_t MN = (size_t)gridDim.y * 128 * N;
  float* C = P + (size_t)kz * MN;
  const int rowS = tid >> 2;
  const int kg = ((tid & 3) ^ ((rowS >> 1) & 3)) * 8;
  const __bf16* gA0 = A + (size_t)(m0 + rowS) * K + kbeg + kg;
  const __bf16* gA1 = gA0 + (size_t)64 * K;
  const __bf16* gB0 = Bt + (size_t)(n0 + rowS) * K + kbeg + kg;
  const __bf16* gB1 = gB0 + (size_t)64 * K;
  const int lo0 = tid * 8, lo1 = 2048 + tid * 8;

  GLD16(gA0, sA[0] + lo0);
  GLD16(gA1, sA[0] + lo1);
  GLD16(gB0, sB[0] + lo0);
  GLD16(gB1, sB[0] + lo1);

  f32x4 acc[4][4] = {};
  for (int i = 0; i < nk; ++i) {
    __syncthreads();
    if (i + 1 < nk) {
      const int k = (i + 1) * 32;
      __bf16* dA = sA[(i + 1) & 1];
      __bf16* dB = sB[(i + 1) & 1];
      GLD16(gA0 + k, dA + lo0);
      GLD16(gA1 + k, dA + lo1);
      GLD16(gB0 + k, dB + lo0);
      GLD16(gB1 + k, dB + lo1);
    }
    const __bf16* cA = sA[i & 1];
    const __bf16* cB = sB[i & 1];
    bf16x8 af[4], bfv[4];
    #pragma unroll
    for (int mt = 0; mt < 4; ++mt) {
      int r = waveM * 64 + mt * 16 + l16;
      af[mt] = *(const bf16x8*)(cA + r * 32 + ((quad ^ ((r >> 1) & 3)) * 8));
    }
    #pragma unroll
    for (int nt = 0; nt < 4; ++nt) {
      int r = waveN * 64 + nt * 16 + l16;
      bfv[nt] = *(const bf16x8*)(cB + r * 32 + ((quad ^ ((r >> 1) & 3)) * 8));
    }
    #pragma unroll
    for (int mt = 0; mt < 4; ++mt)
      #pragma unroll
      for (int nt = 0; nt < 4; ++nt)
        acc[mt][nt] = __builtin_amdgcn_mfma_f32_16x16x32_bf16(af[mt], bfv[nt], acc[mt][nt], 0, 0, 0);
  }
  #pragma unroll
  for (int mt = 0; mt < 4; ++mt) {
    int row = m0 + waveM * 64 + mt * 16 + quad * 4;
    #pragma unroll
    for (int nt = 0; nt < 4; ++nt) {
      int col = n0 + waveN * 64 + nt * 16 + l16;
      #pragma unroll
      for (int r = 0; r < 4; ++r)
        C[(size_t)(row + r) * N + col] = acc[mt][nt][r];
    }
  }
}

// ---------------- fused FFN1 + bias + SwiGLU, 128x128 tile ------------------
// 512 blocks, 2x2 waves; per wave-iter 32 MFMA / 12 ds_read_b128.
// Output goes into concat buffer (stride 5120, col offset 1024).
__global__ __launch_bounds__(256) void ffn1silu_k(
    const __bf16* __restrict__ A, const __bf16* __restrict__ W1t,
    const float* __restrict__ b1, __bf16* __restrict__ ffout) {
  __shared__ __bf16 sA[2][128 * 32];
  __shared__ __bf16 sBx[2][128 * 32];
  __shared__ __bf16 sBg[2][128 * 32];
  const int tid = threadIdx.x, lane = tid & 63, w = tid >> 6;
  const int quad = lane >> 4, l16 = lane & 15;
  const int waveM = w >> 1, waveN = w & 1;
  const int m0 = blockIdx.y * 128, n0 = blockIdx.x * 128;
  const int K = 1024, nk = 32;
  const int rowS = tid >> 2;
  const int kg = ((tid & 3) ^ ((rowS >> 1) & 3)) * 8;
  const __bf16* gA0 = A + (size_t)(m0 + rowS) * K + kg;
  const __bf16* gA1 = gA0 + (size_t)64 * K;
  const __bf16* gBx0 = W1t + (size_t)(n0 + rowS) * K + kg;
  const __bf16* gBx1 = gBx0 + (size_t)64 * K;
  const __bf16* gBg0 = W1t + (size_t)(4096 + n0 + rowS) * K + kg;
  const __bf16* gBg1 = gBg0 + (size_t)64 * K;
  const int lo0 = tid * 8, lo1 = 2048 + tid * 8;

  GLD16(gA0, sA[0] + lo0);
  GLD16(gA1, sA[0] + lo1);
  GLD16(gBx0, sBx[0] + lo0);
  GLD16(gBx1, sBx[0] + lo1);
  GLD16(gBg0, sBg[0] + lo0);
  GLD16(gBg1, sBg[0] + lo1);

  f32x4 ax[4][4] = {}, ag[4][4] = {};
  for (int i = 0; i < nk; ++i) {
    __syncthreads();
    if (i + 1 < nk) {
      const int k = (i + 1) * 32, b = (i + 1) & 1;
      GLD16(gA0 + k, sA[b] + lo0);
      GLD16(gA1 + k, sA[b] + lo1);
      GLD16(gBx0 + k, sBx[b] + lo0);
      GLD16(gBx1 + k, sBx[b] + lo1);
      GLD16(gBg0 + k, sBg[b] + lo0);
      GLD16(gBg1 + k, sBg[b] + lo1);
    }
    const __bf16* cA = sA[i & 1];
    const __bf16* cx = sBx[i & 1];
    const __bf16* cg = sBg[i & 1];
    bf16x8 af[4], bx[4], bg[4];
    #pragma unroll
    for (int mt = 0; mt < 4; ++mt) {
      int r = waveM * 64 + mt * 16 + l16;
      af[mt] = *(const bf16x8*)(cA + r * 32 + ((quad ^ ((r >> 1) & 3)) * 8));
    }
    #pragma unroll
    for (int nt = 0; nt < 4; ++nt) {
      int r = waveN * 64 + nt * 16 + l16;
      int sl = (quad ^ ((r >> 1) & 3)) * 8;
      bx[nt] = *(const bf16x8*)(cx + r * 32 + sl);
      bg[nt] = *(const bf16x8*)(cg + r * 32 + sl);
    }
    #pragma unroll
    for (int mt = 0; mt < 4; ++mt)
      #pragma unroll
      for (int nt = 0; nt < 4; ++nt) {
        ax[mt][nt] = __builtin_amdgcn_mfma_f32_16x16x32_bf16(af[mt], bx[nt], ax[mt][nt], 0, 0, 0);
        ag[mt][nt] = __builtin_amdgcn_mfma_f32_16x16x32_bf16(af[mt], bg[nt], ag[mt][nt], 0, 0, 0);
      }
  }
  #pragma unroll
  for (int mt = 0; mt < 4; ++mt) {
    int row = m0 + waveM * 64 + mt * 16 + quad * 4;
    #pragma unroll
    for (int nt = 0; nt < 4; ++nt) {
      int col = n0 + waveN * 64 + nt * 16 + l16;
      float bxv = b1[col], bgv = b1[col + 4096];
      #pragma unroll
      for (int r = 0; r < 4; ++r) {
        float xp = ax[mt][nt][r] + bxv;
        float g  = ag[mt][nt][r] + bgv;
        float val = xp * g / (1.f + __expf(-g));
        ffout[(size_t)(row + r) * 5120 + 1024 + col] = (__bf16)val;
      }
    }
  }
}

// ---------------- combine: out = Σ4 partials + (bo+b2) + lam*h --------------
__global__ __launch_bounds__(256) void combine_k(
    const float* __restrict__ P, const float* __restrict__ b2,
    const float* __restrict__ bo, const float* __restrict__ hs,
    const float* __restrict__ plam, float* __restrict__ out) {
  const size_t MN = (size_t)2048 * 1024;
  size_t i = ((size_t)blockIdx.x * 256 + threadIdx.x) * 4;
  int col = (int)(i & 1023);
  float4 a0 = *(const float4*)(P + i);
  float4 a1 = *(const float4*)(P + MN + i);
  float4 a2 = *(const float4*)(P + 2 * MN + i);
  float4 a3 = *(const float4*)(P + 3 * MN + i);
  float4 h  = *(const float4*)(hs + i);
  float4 v2 = *(const float4*)(b2 + col);
  float4 vo = *(const float4*)(bo + col);
  float lam = plam[0];
  float4 o;
  o.x = (a0.x + a1.x) + (a2.x + a3.x) + v2.x + vo.x + lam * h.x;
  o.y = (a0.y + a1.y) + (a2.y + a3.y) + v2.y + vo.y + lam * h.y;
  o.z = (a0.z + a1.z) + (a2.z + a3.z) + v2.z + vo.z + lam * h.z;
  o.w = (a0.w + a1.w) + (a2.w + a3.w) + v2.w + vo.w + lam * h.w;
  *(float4*)(out + i) = o;
}

// ---------------- l2norm + RoPE for q,k,qb,kb -------------------------------
__global__ __launch_bounds__(256) void qkprep_k(const float* __restrict__ proj,
    __bf16* __restrict__ qo, __bf16* __restrict__ ko,
    float* __restrict__ qbo, float* __restrict__ kbo) {
  int gw = blockIdx.x * 4 + (threadIdx.x >> 6);
  int lane = threadIdx.x & 63;
  int s = gw >> 4, h = gw & 15;
  int j = lane & 31;
  float inv = powf(1000.0f, -(float)j * (1.0f / 32.0f));
  float ang = (float)s * inv;
  float cb = (float)(__bf16)cosf(ang);
  float sb = (float)(__bf16)sinf(ang);
  size_t ibase = (size_t)s * 5120 + h * 64 + lane;
  size_t obase = (size_t)s * 1024 + h * 64 + lane;
  bool lo = lane < 32;

  auto proc = [&](const float* src) -> float {
    float xv = src[ibase];
    float ss = xv * xv;
    #pragma unroll
    for (int o = 32; o > 0; o >>= 1) ss += __shfl_xor(ss, o);
    float y = xv / fmaxf(sqrtf(ss), 1e-12f);
    float yp = __shfl_xor(y, 32);
    return lo ? (y * cb + yp * sb) : (y * cb - yp * sb);
  };
  qo[obase]  = (__bf16)proc(proj + 0);
  ko[obase]  = (__bf16)proc(proj + 1024);
  qbo[obase] = proc(proj + 3072);
  kbo[obase] = proc(proj + 4096);
}

// ---------------- sb row-sum via two-level cumsum ---------------------------
__global__ __launch_bounds__(64) void kbsum_k(const float* __restrict__ kb,
                                              float* __restrict__ tsum) {
  int t = blockIdx.x, h = blockIdx.y, d = threadIdx.x;
  size_t base = (size_t)h * 64 + d;
  float s = 0.f;
  #pragma unroll 4
  for (int r = 0; r < 32; ++r)
    s += kb[(size_t)(t * 32 + r) * 1024 + base];
  tsum[(t * 16 + h) * 64 + d] = s;
}

__global__ __launch_bounds__(64) void sbrow2_k(const float* __restrict__ qb,
                                               const float* __restrict__ kb,
                                               const float* __restrict__ tsum,
                                               float* __restrict__ sb) {
  int t = blockIdx.x, h = blockIdx.y, d = threadIdx.x;
  size_t base = (size_t)h * 64 + d;
  float run = 0.f;
  for (int tp = 0; tp < t; ++tp) run += tsum[(tp * 16 + h) * 64 + d];
  for (int s0 = 0; s0 < 32; s0 += 4) {
    float p[4];
    #pragma unroll
    for (int u = 0; u < 4; ++u) {
      size_t off = (size_t)(t * 32 + s0 + u) * 1024 + base;
      run += kb[off];
      p[u] = qb[off] * run;
    }
    #pragma unroll
    for (int o = 32; o > 0; o >>= 1) {
      #pragma unroll
      for (int u = 0; u < 4; ++u) p[u] += __shfl_xor(p[u], o);
    }
    if (d == 0) {
      #pragma unroll
      for (int u = 0; u < 4; ++u) sb[(t * 32 + s0 + u) * 16 + h] = 0.125f * p[u];
    }
  }
}

// ---------------- flash attention: split-KV x4, swizzled LDS ----------------
__global__ __launch_bounds__(256) void attn_k(const __bf16* __restrict__ qg,
    const __bf16* __restrict__ kg, const __bf16* __restrict__ vtg,
    float* __restrict__ o_part, float* __restrict__ m_part,
    float* __restrict__ l_part) {
  __shared__ __bf16 sK[64 * 64];
  __shared__ __bf16 sVt[64 * 64];
  __shared__ __bf16 sP[4][16 * 64];
  const int pair = blockIdx.x, j4 = blockIdx.y, hh = blockIdx.z;
  const int tid = threadIdx.x, lane = tid & 63, w = tid >> 6;
  const int quad = lane >> 4, l16 = lane & 15;
  const int srow = tid >> 3;
  const int sg = (tid & 7) ^ (srow & 7);
  __bf16* ldsK = sK + tid * 8;
  __bf16* ldsV = sVt + tid * 8;
  __bf16* sPw = sP[w];

  for (int phase = 0; phase < 2; ++phase) {
    const int qt = phase ? 31 - pair : pair;
    const int q0 = qt * 64;
    const int n = qt + 1;
    const int kb = (j4 * n) >> 2, ke = ((j4 + 1) * n) >> 2;
    bf16x8 qf[2];
    #pragma unroll
    for (int kk = 0; kk < 2; ++kk)
      qf[kk] = *(const bf16x8*)(qg + (size_t)(q0 + w * 16 + l16) * 1024 + hh * 64 + kk * 32 + quad * 8);
    f32x4 accO[4] = {};
    float m_[4], l_[4];
    #pragma unroll
    for (int r = 0; r < 4; ++r) { m_[r] = -INFINITY; l_[r] = 0.f; }

    for (int kt = kb; kt < ke; ++kt) {
      const __bf16* gK = kg + (size_t)(kt * 64 + srow) * 1024 + hh * 64 + sg * 8;
      const __bf16* gV = vtg + (size_t)(hh * 64 + srow) * 2048 + kt * 64 + sg * 8;
      GLD16(gK, ldsK);
      GLD16(gK + (size_t)32 * 1024, ldsK + 2048);
      GLD16(gV, ldsV);
      GLD16(gV + (size_t)32 * 2048, ldsV + 2048);
      __syncthreads();

      f32x4 s4[4];
      #pragma unroll
      for (int nt = 0; nt < 4; ++nt) {
        int r = nt * 16 + l16;
        bf16x8 b0 = *(const bf16x8*)(sK + r * 64 + ((quad ^ (r & 7)) * 8));
        bf16x8 b1 = *(const bf16x8*)(sK + r * 64 + (((4 + quad) ^ (r & 7)) * 8));
        f32x4 sa = {0.f, 0.f, 0.f, 0.f};
        sa = __builtin_amdgcn_mfma_f32_16x16x32_bf16(qf[0], b0, sa, 0, 0, 0);
        sa = __builtin_amdgcn_mfma_f32_16x16x32_bf16(qf[1], b1, sa, 0, 0, 0);
        s4[nt] = sa;
      }
      if (kt == qt) {
        #pragma unroll
        for (int nt = 0; nt < 4; ++nt)
          #pragma unroll
          for (int r = 0; r < 4; ++r)
            if (nt * 16 + l16 > w * 16 + quad * 4 + r) s4[nt][r] = -INFINITY;
      }
      float mx[4], al[4], rs[4];
      #pragma unroll
      for (int r = 0; r < 4; ++r)
        mx[r] = fmaxf(fmaxf(s4[0][r], s4[1][r]), fmaxf(s4[2][r], s4[3][r]));
      #pragma unroll
      for (int o = 1; o < 16; o <<= 1)
        #pragma unroll
        for (int r = 0; r < 4; ++r) mx[r] = fmaxf(mx[r], __shfl_xor(mx[r], o));
      #pragma unroll
      for (int r = 0; r < 4; ++r) {
        float mn = fmaxf(m_[r], mx[r]);
        al[r] = __expf(m_[r] - mn);
        m_[r] = mn;
      }
      float p[4][4];
      #pragma unroll
      for (int nt = 0; nt < 4; ++nt)
        #pragma unroll
        for (int r = 0; r < 4; ++r)
          p[nt][r] = __expf(s4[nt][r] - m_[r]);
      #pragma unroll
      for (int r = 0; r < 4; ++r)
        rs[r] = (p[0][r] + p[1][r]) + (p[2][r] + p[3][r]);
      #pragma unroll
      for (int o = 1; o < 16; o <<= 1)
        #pragma unroll
        for (int r = 0; r < 4; ++r) rs[r] += __shfl_xor(rs[r], o);
      #pragma unroll
      for (int r = 0; r < 4; ++r) l_[r] = l_[r] * al[r] + rs[r];
      #pragma unroll
      for (int nt = 0; nt < 4; ++nt)
        #pragma unroll
        for (int r = 0; r < 4; ++r) accO[nt][r] *= al[r];
      #pragma unroll
      for (int nt = 0; nt < 4; ++nt)
        #pragma unroll
        for (int r = 0; r < 4; ++r) {
          int row = quad * 4 + r, col = nt * 16 + l16;
          sPw[row * 64 + (col ^ ((row & 7) << 3))] = (__bf16)p[nt][r];
        }
      #pragma unroll
      for (int kk = 0; kk < 2; ++kk) {
        bf16x8 a = *(const bf16x8*)(sPw + l16 * 64 + (((kk * 4 + quad) ^ (l16 & 7)) * 8));
        #pragma unroll
        for (int nt = 0; nt < 4; ++nt) {
          int vr = nt * 16 + l16;
          bf16x8 bv = *(const bf16x8*)(sVt + vr * 64 + (((kk * 4 + quad) ^ (vr & 7)) * 8));
          accO[nt] = __builtin_amdgcn_mfma_f32_16x16x32_bf16(a, bv, accO[nt], 0, 0, 0);
        }
      }
      __syncthreads();
    }
    #pragma unroll
    for (int r = 0; r < 4; ++r) {
      int grow = q0 + w * 16 + quad * 4 + r;
      if (l16 == 0) {
        m_part[((size_t)j4 * 2048 + grow) * 16 + hh] = m_[r];
        l_part[((size_t)j4 * 2048 + grow) * 16 + hh] = l_[r];
      }
      #pragma unroll
      for (int nt = 0; nt < 4; ++nt)
        o_part[((size_t)j4 * 2048 + grow) * 1024 + hh * 64 + nt * 16 + l16] = accO[nt][r];
    }
  }
}

// ---------------- merge 4 KV-partials -> y into concat (stride 5120) --------
__global__ __launch_bounds__(256) void attnmerge_k(const float* __restrict__ o_part,
    const float* __restrict__ m_part, const float* __restrict__ l_part,
    const float* __restrict__ sbr, const float* __restrict__ pl2s,
    __bf16* __restrict__ yo) {
  int idx = blockIdx.x * 256 + threadIdx.x;
  int s = idx >> 8, rem = idx & 255;
  int h = rem >> 4, dg = (rem & 15) * 4;
  float m[4], l[4];
  #pragma unroll
  for (int j = 0; j < 4; ++j) {
    m[j] = m_part[((size_t)j * 2048 + s) * 16 + h];
    l[j] = l_part[((size_t)j * 2048 + s) * 16 + h];
  }
  float M = fmaxf(fmaxf(m[0], m[1]), fmaxf(m[2], m[3]));
  float den = 0.f;
  float4 acc = {0.f, 0.f, 0.f, 0.f};
  #pragma unroll
  for (int j = 0; j < 4; ++j) {
    float e = __expf(m[j] - M);
    den += l[j] * e;
    float4 o = *(const float4*)(o_part + ((size_t)j * 2048 + s) * 1024 + h * 64 + dg);
    acc.x += e * o.x; acc.y += e * o.y; acc.z += e * o.z; acc.w += e * o.w;
  }
  float sc = pl2s[0] / den;
  float add = sbr[s * 16 + h];
  __bf16* yp = yo + (size_t)s * 5120 + h * 64 + dg;
  yp[0] = (__bf16)(sc * acc.x + add);
  yp[1] = (__bf16)(sc * acc.y + add);
  yp[2] = (__bf16)(sc * acc.z + add);
  yp[3] = (__bf16)(sc * acc.w + add);
}

extern "C" void kernel_launch(void* const* d_in, const int* in_sizes, int n_in,
                              void* d_out, int out_size, void* d_ws, size_t ws_size,
                              hipStream_t stream) {
  (void)in_sizes; (void)n_in; (void)out_size; (void)ws_size;
  const float* hs   = (const float*)d_in[0];
  const float* Wq   = (const float*)d_in[1];
  const float* Wk   = (const float*)d_in[2];
  const float* Wv   = (const float*)d_in[3];
  const float* Wqb  = (const float*)d_in[4];
  const float* Wkb  = (const float*)d_in[5];
  const float* Wo   = (const float*)d_in[6];
  const float* bo   = (const float*)d_in[7];
  const float* W1   = (const float*)d_in[8];
  const float* b1   = (const float*)d_in[9];
  const float* W2   = (const float*)d_in[10];
  const float* b2   = (const float*)d_in[11];
  const float* plam = (const float*)d_in[12];
  const float* pl2s = (const float*)d_in[13];
  float* out = (float*)d_out;
  char* ws = (char*)d_ws;

  size_t off = 0;
  auto alloc = [&](size_t bytes) { char* p = ws + off; off += (bytes + 255) & ~(size_t)255; return p; };
  __bf16* Wt5    = (__bf16*)alloc((size_t)5 * 1024 * 1024 * 2);
  __bf16* WoW2t  = (__bf16*)alloc((size_t)1024 * 5120 * 2);   // [n][k], k: Wo 0..1023, W2 1024..5119
  __bf16* W1t    = (__bf16*)alloc((size_t)8192 * 1024 * 2);
  __bf16* xbf    = (__bf16*)alloc((size_t)2048 * 1024 * 2);
  __bf16* concat = (__bf16*)alloc((size_t)2048 * 5120 * 2);   // [y | ffin] bf16
  float*  proj  = (float*)alloc((size_t)2048 * 5120 * 4);
  float*  qbf32 = (float*)alloc((size_t)2048 * 1024 * 4);
  float*  kbf32 = (float*)alloc((size_t)2048 * 1024 * 4);
  __bf16* qbf   = (__bf16*)alloc((size_t)2048 * 1024 * 2);
  __bf16* kbf   = (__bf16*)alloc((size_t)2048 * 1024 * 2);
  float*  o_part = proj;                                      // 4 x 8 MB (proj dead after prep)
  float*  m_part = qbf32;                                     // 512 KB
  float*  l_part = qbf32 + (size_t)4 * 2048 * 16;             // 512 KB
  float*  gpart  = proj;                                      // 4 x 8 MB (after attnmerge)
  __bf16* vtbf  = (__bf16*)alloc((size_t)1024 * 2048 * 2);
  float*  sbrow = (float*)alloc((size_t)2048 * 16 * 4);
  float*  tsum  = (float*)alloc((size_t)64 * 16 * 64 * 4);

  // weight repack (batched)
  tconv5_k<<<dim3(32, 32, 5), 256, 0, stream>>>(Wq, Wk, Wv, Wqb, Wkb, Wt5);
  tconvwow2_k<<<dim3(32, 128, 2), 256, 0, stream>>>(Wo, W2, WoW2t);
  tconv_k<<<dim3(256, 32), 256, 0, stream>>>(W1, W1t, 8192, 1024);

  rmsnorm_k<<<2048, 256, 0, stream>>>(hs, xbf);
  gemm_bt_k<<<dim3(40, 16), 256, 0, stream>>>(xbf, Wt5, proj, 5120, 1024);
  qkprep_k<<<8192, 256, 0, stream>>>(proj, qbf, kbf, qbf32, kbf32);
  tconv_k<<<dim3(32, 64), 256, 0, stream>>>(proj + 2048, vtbf, 5120, 2048);
  kbsum_k<<<dim3(64, 16), 64, 0, stream>>>(kbf32, tsum);
  sbrow2_k<<<dim3(64, 16), 64, 0, stream>>>(qbf32, kbf32, tsum, sbrow);
  attn_k<<<dim3(16, 4, 16), 256, 0, stream>>>(qbf, kbf, vtbf, o_part, m_part, l_part);
  attnmerge_k<<<2048, 256, 0, stream>>>(o_part, m_part, l_part, sbrow, pl2s, concat);
  // fused FFN1 + bias + SwiGLU -> concat cols 1024..5119
  ffn1silu_k<<<dim3(32, 16), 256, 0, stream>>>(xbf, W1t, b1, concat);
  // merged (Wo + FFN2): [y|ffin] @ [Wo;W2], K=5120, split-K x4 -> partials
  gemm_partk_k<<<dim3(8, 16, 4), 256, 0, stream>>>(concat, WoW2t, gpart, 1024, 5120);
  // out = Σ partials + (bo+b2) + lam*h
  combine_k<<<2048, 256, 0, stream>>>(gpart, b2, bo, hs, plam, out);
}